// Round 5
// baseline (919.272 us; speedup 1.0000x reference)
//
#include <hip/hip_runtime.h>
#include <math.h>

namespace {
constexpr int Bc = 64, Lc = 256, DMc = 256;
constexpr int NTc = 20, START_c = 18, STOP_c = 19;
constexpr int ROWSc = Bc * Lc;  // 16384
}

typedef short short8 __attribute__((ext_vector_type(8)));
typedef float f32x4 __attribute__((ext_vector_type(4)));
typedef ushort ushort4v __attribute__((ext_vector_type(4)));

__device__ __forceinline__ ushort f2bf(float x) {
  unsigned u = __float_as_uint(x);
  unsigned r = (u + 0x7FFFu + ((u >> 16) & 1u)) >> 16;
  return (ushort)r;
}
__device__ __forceinline__ float bf2f(ushort h) {
  return __uint_as_float((unsigned)h << 16);
}
__device__ __forceinline__ float fast_sig(float x) {
  return __fdividef(1.f, 1.f + __expf(-x));
}
__device__ __forceinline__ float fast_tanh(float x) {
  return 1.f - __fdividef(2.f, 1.f + __expf(2.f * x));
}
// LDS-only barrier: no vmcnt(0) drain (out-stores / prefetch loads stay in flight).
__device__ __forceinline__ void lds_barrier() {
  asm volatile("s_waitcnt lgkmcnt(0)" ::: "memory");
  __builtin_amdgcn_s_barrier();
  asm volatile("" ::: "memory");
}

// ---------------- fin (bf16) = concat(emb1[sent], emb2[bush], pinyin, trans_weizhi, weizhi) ----------------
__global__ __launch_bounds__(256) void build_fin_k(
    const int* __restrict__ sent, const int* __restrict__ bush,
    const float* __restrict__ pin, const float* __restrict__ wz,
    const float* __restrict__ twz, const float* __restrict__ emb1,
    const float* __restrict__ emb2, ushort* __restrict__ finb) {
  const int row = blockIdx.x;
  const int c = threadIdx.x;
  float v;
  if (c < 100)      v = emb1[(size_t)sent[row] * 100 + c];
  else if (c < 200) v = emb2[(size_t)bush[row] * 100 + (c - 100)];
  else if (c < 220) v = pin[(size_t)row * 20 + (c - 200)];
  else if (c < 238) v = twz[(size_t)row * 18 + (c - 220)];
  else              v = wz[(size_t)row * 18 + (c - 238)];
  finb[(size_t)row * 256 + c] = f2bf(v);
}

// ---------------- pack weights/biases to bf16 ----------------
__global__ __launch_bounds__(256) void pack_weights_k(
    const float* __restrict__ Wq, const float* __restrict__ Wk,
    const float* __restrict__ Wv, const float* __restrict__ Wo,
    const float* __restrict__ Wihf, const float* __restrict__ Wihb,
    const float* __restrict__ bq, const float* __restrict__ bk,
    const float* __restrict__ bv, const float* __restrict__ bihf,
    const float* __restrict__ bihb,
    ushort* __restrict__ wqkv, ushort* __restrict__ wih, ushort* __restrict__ wo,
    float* __restrict__ bqkv, float* __restrict__ bih) {
  const int gid = blockIdx.x * 256 + threadIdx.x;  // 65536 threads
  const int row = gid >> 5;
  const int cl = (gid & 31) * 8;
  const float* src;
  ushort* dst;
  if (row < 768) {
    src = (row < 256 ? Wq : (row < 512 ? Wk : Wv)) + (size_t)(row & 255) * 256;
    dst = wqkv + (size_t)row * 256;
  } else if (row < 1792) {
    const int rr = row - 768;
    src = (rr < 512 ? Wihf + (size_t)rr * 256 : Wihb + (size_t)(rr - 512) * 256);
    dst = wih + (size_t)rr * 256;
  } else {
    const int rr = row - 1792;
    src = Wo + (size_t)rr * 256;
    dst = wo + (size_t)rr * 256;
  }
  float4 v0 = *(const float4*)(src + cl);
  float4 v1 = *(const float4*)(src + cl + 4);
  short8 o;
  o[0] = (short)f2bf(v0.x); o[1] = (short)f2bf(v0.y); o[2] = (short)f2bf(v0.z); o[3] = (short)f2bf(v0.w);
  o[4] = (short)f2bf(v1.x); o[5] = (short)f2bf(v1.y); o[6] = (short)f2bf(v1.z); o[7] = (short)f2bf(v1.w);
  *(short8*)(dst + cl) = o;
  if (gid < 768) {
    bqkv[gid] = (gid < 256 ? bq[gid] : (gid < 512 ? bk[gid - 256] : bv[gid - 512]));
  } else if (gid < 1792) {
    bih[gid - 768] = (gid < 1280 ? bihf[gid - 768] : bihb[gid - 1280]);
  }
}

// ---------------- pack Whh (2x512x128) to bf16 ----------------
__global__ __launch_bounds__(256) void pack_whh_k(
    const float* __restrict__ Whhf, const float* __restrict__ Whhb,
    ushort* __restrict__ whh) {
  const int gid = blockIdx.x * 256 + threadIdx.x;  // 16384 threads
  const int idx = gid * 8;                          // into 131072
  const float* src = (idx < 65536) ? (Whhf + idx) : (Whhb + (idx - 65536));
  float4 v0 = *(const float4*)(src);
  float4 v1 = *(const float4*)(src + 4);
  short8 o;
  o[0] = (short)f2bf(v0.x); o[1] = (short)f2bf(v0.y); o[2] = (short)f2bf(v0.z); o[3] = (short)f2bf(v0.w);
  o[4] = (short)f2bf(v1.x); o[5] = (short)f2bf(v1.y); o[6] = (short)f2bf(v1.z); o[7] = (short)f2bf(v1.w);
  *(short8*)(whh + idx) = o;
}

// ---------------- bf16 MFMA GEMM: C[m,n] = sum_k A[m,k]*W[n,k] + bias[n]; K=256, 128x128 tile ----------------
template <int N, bool BF16_OUT>
__global__ __launch_bounds__(256, 2) void mfma_gemm_k(
    const ushort* __restrict__ A, const ushort* __restrict__ W,
    const float* __restrict__ bias, void* __restrict__ Cv) {
  const int tid = threadIdx.x, lane = tid & 63, wid = tid >> 6;
  const int bm = blockIdx.x * 128, bn = blockIdx.y * 128;
  const int wm = (wid >> 1) * 64, wn = (wid & 1) * 64;
  const int r = lane & 15, kg = lane >> 4;
  const ushort* Ap = A + (size_t)(bm + wm + r) * 256 + kg * 8;
  const ushort* Wp = W + (size_t)(bn + wn + r) * 256 + kg * 8;
  f32x4 acc[4][4];
#pragma unroll
  for (int i = 0; i < 4; ++i)
#pragma unroll
    for (int j = 0; j < 4; ++j) acc[i][j] = (f32x4){0.f, 0.f, 0.f, 0.f};
#pragma unroll
  for (int k0 = 0; k0 < 256; k0 += 32) {
    short8 a[4], b[4];
#pragma unroll
    for (int fi = 0; fi < 4; ++fi) a[fi] = *(const short8*)(Ap + fi * 16 * 256 + k0);
#pragma unroll
    for (int fj = 0; fj < 4; ++fj) b[fj] = *(const short8*)(Wp + fj * 16 * 256 + k0);
#pragma unroll
    for (int fi = 0; fi < 4; ++fi)
#pragma unroll
      for (int fj = 0; fj < 4; ++fj)
        acc[fi][fj] = __builtin_amdgcn_mfma_f32_16x16x32_bf16(a[fi], b[fj], acc[fi][fj], 0, 0, 0);
  }
#pragma unroll
  for (int fi = 0; fi < 4; ++fi)
#pragma unroll
    for (int fj = 0; fj < 4; ++fj) {
      const int n = bn + wn + fj * 16 + r;
      const float bn_ = bias[n];
#pragma unroll
      for (int rr = 0; rr < 4; ++rr) {
        const int m = bm + wm + fi * 16 + kg * 4 + rr;
        const float v = acc[fi][fj][rr] + bn_;
        if (BF16_OUT) ((ushort*)Cv)[(size_t)m * N + n] = f2bf(v);
        else          ((float*)Cv)[(size_t)m * N + n] = v;
      }
    }
}

// ---------------- attention: one block per (b,h,qhalf); qkv packed [ROWS][768] fp32; out bf16 ----------
__global__ __launch_bounds__(256) void attn_k(
    const float* __restrict__ qkv, ushort* __restrict__ xout) {
  const int bh = blockIdx.x >> 1, qh = blockIdx.x & 1;
  const int b = bh >> 2, h = bh & 3;
  const int tid = threadIdx.x;
  const int lane = tid & 63, w = tid >> 6;
  __shared__ __align__(16) float qs[4][64];
  __shared__ __align__(16) float pl[4][256];
  __shared__ float red[4][4];
  __shared__ float pvp[4][4][64];
  const float* qb = qkv + (size_t)(b * Lc) * 768 + h * 64;
  const float* kb = qb + 256;
  const float* vb = qb + 512;
  float4 kr4[16], vr4[16];
#pragma unroll
  for (int c4 = 0; c4 < 16; ++c4) kr4[c4] = *(const float4*)(kb + (size_t)tid * 768 + c4 * 4);
#pragma unroll
  for (int j4 = 0; j4 < 16; ++j4) {
    float4 t;
    t.x = vb[(size_t)(w * 64 + j4 * 4 + 0) * 768 + lane];
    t.y = vb[(size_t)(w * 64 + j4 * 4 + 1) * 768 + lane];
    t.z = vb[(size_t)(w * 64 + j4 * 4 + 2) * 768 + lane];
    t.w = vb[(size_t)(w * 64 + j4 * 4 + 3) * 768 + lane];
    vr4[j4] = t;
  }

  for (int q0 = qh * 128; q0 < qh * 128 + 128; q0 += 4) {
    lds_barrier();
    qs[w][lane] = qb[(size_t)(q0 + w) * 768 + lane];
    lds_barrier();
    float s0 = 0, s1 = 0, s2 = 0, s3 = 0;
#pragma unroll
    for (int d4 = 0; d4 < 16; ++d4) {
      float4 kv = kr4[d4];
      float4 q0v = *(const float4*)(&qs[0][d4 * 4]);
      float4 q1v = *(const float4*)(&qs[1][d4 * 4]);
      float4 q2v = *(const float4*)(&qs[2][d4 * 4]);
      float4 q3v = *(const float4*)(&qs[3][d4 * 4]);
      s0 += kv.x * q0v.x + kv.y * q0v.y + kv.z * q0v.z + kv.w * q0v.w;
      s1 += kv.x * q1v.x + kv.y * q1v.y + kv.z * q1v.z + kv.w * q1v.w;
      s2 += kv.x * q2v.x + kv.y * q2v.y + kv.z * q2v.z + kv.w * q2v.w;
      s3 += kv.x * q3v.x + kv.y * q3v.y + kv.z * q3v.z + kv.w * q3v.w;
    }
    s0 *= 0.125f; s1 *= 0.125f; s2 *= 0.125f; s3 *= 0.125f;
    float m0 = s0, m1 = s1, m2 = s2, m3 = s3;
#pragma unroll
    for (int off = 32; off > 0; off >>= 1) {
      m0 = fmaxf(m0, __shfl_xor(m0, off));
      m1 = fmaxf(m1, __shfl_xor(m1, off));
      m2 = fmaxf(m2, __shfl_xor(m2, off));
      m3 = fmaxf(m3, __shfl_xor(m3, off));
    }
    if (lane == 0) { red[w][0] = m0; red[w][1] = m1; red[w][2] = m2; red[w][3] = m3; }
    lds_barrier();
    const float M0 = fmaxf(fmaxf(red[0][0], red[1][0]), fmaxf(red[2][0], red[3][0]));
    const float M1 = fmaxf(fmaxf(red[0][1], red[1][1]), fmaxf(red[2][1], red[3][1]));
    const float M2 = fmaxf(fmaxf(red[0][2], red[1][2]), fmaxf(red[2][2], red[3][2]));
    const float M3 = fmaxf(fmaxf(red[0][3], red[1][3]), fmaxf(red[2][3], red[3][3]));
    const float e0 = __expf(s0 - M0), e1 = __expf(s1 - M1), e2 = __expf(s2 - M2), e3 = __expf(s3 - M3);
    pl[0][tid] = e0; pl[1][tid] = e1; pl[2][tid] = e2; pl[3][tid] = e3;
    float t0 = e0, t1 = e1, t2 = e2, t3 = e3;
#pragma unroll
    for (int off = 32; off > 0; off >>= 1) {
      t0 += __shfl_xor(t0, off); t1 += __shfl_xor(t1, off);
      t2 += __shfl_xor(t2, off); t3 += __shfl_xor(t3, off);
    }
    lds_barrier();
    if (lane == 0) { red[w][0] = t0; red[w][1] = t1; red[w][2] = t2; red[w][3] = t3; }
    lds_barrier();
    float a0 = 0, a1 = 0, a2 = 0, a3 = 0;
#pragma unroll
    for (int j4 = 0; j4 < 16; ++j4) {
      float4 vv = vr4[j4];
      float4 p0 = *(const float4*)(&pl[0][w * 64 + j4 * 4]);
      float4 p1 = *(const float4*)(&pl[1][w * 64 + j4 * 4]);
      float4 p2 = *(const float4*)(&pl[2][w * 64 + j4 * 4]);
      float4 p3 = *(const float4*)(&pl[3][w * 64 + j4 * 4]);
      a0 += p0.x * vv.x + p0.y * vv.y + p0.z * vv.z + p0.w * vv.w;
      a1 += p1.x * vv.x + p1.y * vv.y + p1.z * vv.z + p1.w * vv.w;
      a2 += p2.x * vv.x + p2.y * vv.y + p2.z * vv.z + p2.w * vv.w;
      a3 += p3.x * vv.x + p3.y * vv.y + p3.z * vv.z + p3.w * vv.w;
    }
    pvp[w][0][lane] = a0; pvp[w][1][lane] = a1; pvp[w][2][lane] = a2; pvp[w][3][lane] = a3;
    lds_barrier();
    const float den = red[0][w] + red[1][w] + red[2][w] + red[3][w];
    const float rres = (pvp[0][w][lane] + pvp[1][w][lane] + pvp[2][w][lane] + pvp[3][w][lane]) / den;
    xout[((size_t)b * Lc + q0 + w) * 256 + h * 64 + lane] = f2bf(rres);
  }
}

// ---------------- MFMA BiLSTM: block (bslice, dir); 512 thr = 8 waves; wave w owns units w*16..+15 ----------
// Per step: gates[512][16] = Whh(512x128, regs) x h(128x16, LDS). Raw barriers (no vmcnt drain);
// gx prefetched 2 steps ahead in named register sets (gA even steps, gB odd).
__global__ __launch_bounds__(512, 2) void lstm_mfma_k(
    const ushort* __restrict__ gx, const ushort* __restrict__ whh,
    const float* __restrict__ bhhf, const float* __restrict__ bhhb,
    const float* __restrict__ h0, const float* __restrict__ c0,
    ushort* __restrict__ out) {
  const int bs = blockIdx.x * 16;
  const int dir = blockIdx.y;
  const int tid = threadIdx.x;
  const int w = tid >> 6, lane = tid & 63;
  const int col = lane & 15;  // batch within slice
  const int kg = lane >> 4;   // 0..3
  short8 afrag[4][4];
#pragma unroll
  for (int g = 0; g < 4; ++g)
#pragma unroll
    for (int ks = 0; ks < 4; ++ks)
      afrag[g][ks] = *(const short8*)(whh + (size_t)dir * 65536 +
                                      (size_t)(g * 128 + w * 16 + col) * 128 + ks * 32 + kg * 8);
  const float* bhh = dir ? bhhb : bhhf;
  float4 bias4[4];
#pragma unroll
  for (int g = 0; g < 4; ++g) bias4[g] = *(const float4*)(bhh + g * 128 + w * 16 + kg * 4);
  float4 c4 = *(const float4*)(c0 + (size_t)(dir * Bc + bs + col) * 128 + w * 16 + kg * 4);
  __shared__ __align__(16) ushort hlds[2][2048];
  {
    float4 h4 = *(const float4*)(h0 + (size_t)(dir * Bc + bs + col) * 128 + w * 16 + kg * 4);
    ushort4v hp;
    hp.x = f2bf(h4.x); hp.y = f2bf(h4.y); hp.z = f2bf(h4.z); hp.w = f2bf(h4.w);
    const int wb = (col * 256 + w * 32 + kg * 8) ^ ((col & 7) << 4);
    *(ushort4v*)((char*)hlds[0] + wb) = hp;
  }
  const ushort* gbase = gx + (size_t)(bs + col) * Lc * 1024 + dir * 512 + w * 16 + kg * 4;
  int step = dir ? (Lc - 1) : 0;
  const int dstep = dir ? -1 : 1;
  ushort4v gA[4], gB[4];
#pragma unroll
  for (int g = 0; g < 4; ++g) gA[g] = *(const ushort4v*)(gbase + (size_t)step * 1024 + g * 128);
#pragma unroll
  for (int g = 0; g < 4; ++g) gB[g] = *(const ushort4v*)(gbase + (size_t)(step + dstep) * 1024 + g * 128);
  __syncthreads();
  int p = 0;

  auto body = [&](ushort4v (&gcur)[4], int pfstep, bool pfok) {
    short8 bfrag[4];
#pragma unroll
    for (int ks = 0; ks < 4; ++ks) {
      const int rb = (col * 256 + ks * 64 + kg * 16) ^ ((col & 7) << 4);
      bfrag[ks] = *(const short8*)((const char*)hlds[p] + rb);
    }
    ushort4v gxc[4];
#pragma unroll
    for (int g = 0; g < 4; ++g) gxc[g] = gcur[g];
    if (pfok) {
#pragma unroll
      for (int g = 0; g < 4; ++g) gcur[g] = *(const ushort4v*)(gbase + (size_t)pfstep * 1024 + g * 128);
    }
    f32x4 acc[4];
#pragma unroll
    for (int g = 0; g < 4; ++g) acc[g] = (f32x4){0.f, 0.f, 0.f, 0.f};
#pragma unroll
    for (int ks = 0; ks < 4; ++ks)
#pragma unroll
      for (int g = 0; g < 4; ++g)
        acc[g] = __builtin_amdgcn_mfma_f32_16x16x32_bf16(afrag[g][ks], bfrag[ks], acc[g], 0, 0, 0);
    ushort4v hp;
#pragma unroll
    for (int r = 0; r < 4; ++r) {
      const float ii = fast_sig (acc[0][r] + bf2f(gxc[0][r]) + bias4[0][r]);
      const float ff = fast_sig (acc[1][r] + bf2f(gxc[1][r]) + bias4[1][r]);
      const float gg = fast_tanh(acc[2][r] + bf2f(gxc[2][r]) + bias4[2][r]);
      const float oo = fast_sig (acc[3][r] + bf2f(gxc[3][r]) + bias4[3][r]);
      const float cn = ff * c4[r] + ii * gg;
      c4[r] = cn;
      hp[r] = f2bf(oo * fast_tanh(cn));
    }
    const int wb = (col * 256 + w * 32 + kg * 8) ^ ((col & 7) << 4);
    *(ushort4v*)((char*)hlds[p ^ 1] + wb) = hp;
    *(ushort4v*)(out + ((size_t)((bs + col) * Lc + step)) * 256 + dir * 128 + w * 16 + kg * 4) = hp;
    // LDS-only barrier: h exchange needs lgkmcnt; out-store & gx prefetch stay in flight.
    asm volatile("s_waitcnt lgkmcnt(0)" ::: "memory");
    __builtin_amdgcn_s_barrier();
    asm volatile("" ::: "memory");
    p ^= 1;
    step += dstep;
  };

  for (int s = 0; s < Lc; s += 2) {
    const int pf1 = step + 2 * dstep;
    body(gA, pf1, s + 2 < Lc);
    const int pf2 = step + 2 * dstep;
    body(gB, pf2, s + 3 < Lc);
  }
}

// ---------------- logits = lstm_out(bf16) @ Wout.T + bout  (N=20) ----------------
__global__ __launch_bounds__(256) void logits_k(
    const ushort* __restrict__ lo, const float* __restrict__ Wout,
    const float* __restrict__ bout, float* __restrict__ lg) {
  const int row = blockIdx.x;
  const int tid = threadIdx.x;
  __shared__ __align__(16) float xr[256];
  xr[tid] = bf2f(lo[(size_t)row * 256 + tid]);
  __syncthreads();
  if (tid < 160) {
    const int n = tid >> 3, kp = tid & 7;
    const float* wr = Wout + (size_t)n * 256 + kp * 32;
    const float* xp = xr + kp * 32;
    float s = 0.f;
#pragma unroll
    for (int k = 0; k < 32; k += 4) {
      float4 wv = *(const float4*)(wr + k);
      float4 xv = *(const float4*)(xp + k);
      s += wv.x * xv.x + wv.y * xv.y + wv.z * xv.z + wv.w * xv.w;
    }
    s += __shfl_xor(s, 1);
    s += __shfl_xor(s, 2);
    s += __shfl_xor(s, 4);
    if (kp == 0) lg[(size_t)row * NTc + n] = s + bout[n];
  }
}

// ---------------- CRF: gold score + forward logsumexp scan; writes total - real ----------------
__global__ __launch_bounds__(64) void crf_fwd_k(
    const float* __restrict__ lg, const int* __restrict__ tags,
    const int* __restrict__ lens, const float* __restrict__ tr,
    float* __restrict__ part) {
  const int b = blockIdx.x, j = threadIdx.x;
  __shared__ float prev[NTc];
  __shared__ float tl[NTc * NTc];
  if (j < NTc) prev[j] = 0.f;
  for (int i = j; i < NTc * NTc; i += 64) tl[i] = tr[i];
  __syncthreads();
  const int len = lens[b];
  float gv = 0.f;
  for (int t = j; t < len; t += 64) {
    const int tag = tags[b * Lc + t];
    const int pv = (t == 0) ? START_c : tags[b * Lc + t - 1];
    gv += lg[((size_t)b * Lc + t) * NTc + tag] + tl[pv * NTc + tag];
  }
#pragma unroll
  for (int off = 32; off > 0; off >>= 1) gv += __shfl_xor(gv, off);
  float trc[NTc];
  if (j < NTc) {
#pragma unroll
    for (int i = 0; i < NTc; ++i) trc[i] = tl[i * NTc + j];
  }
  float lgn = (j < NTc) ? lg[((size_t)b * Lc) * NTc + j] : 0.f;
  for (int t = 0; t < len; ++t) {
    const float lgc = lgn;
    float nj = 0.f;
    if (j < NTc) {
      if (t + 1 < len) lgn = lg[((size_t)b * Lc + t + 1) * NTc + j];
      float v[NTc];
      float m = -1e30f;
#pragma unroll
      for (int i = 0; i < NTc; ++i) { v[i] = prev[i] + trc[i]; m = fmaxf(m, v[i]); }
      float ssum = 0.f;
#pragma unroll
      for (int i = 0; i < NTc; ++i) ssum += __expf(v[i] - m);
      nj = m + __logf(ssum) + lgc;
    }
    __syncthreads();
    if (j < NTc) prev[j] = nj;
    __syncthreads();
  }
  if (j == 0) {
    const int lt = tags[b * Lc + len - 1];
    const float realv = gv + tl[lt * NTc + STOP_c];
    float m = -1e30f;
#pragma unroll
    for (int i = 0; i < NTc; ++i) m = fmaxf(m, prev[i] + tl[i * NTc + STOP_c]);
    float ssum = 0.f;
#pragma unroll
    for (int i = 0; i < NTc; ++i) ssum += __expf(prev[i] + tl[i * NTc + STOP_c] - m);
    part[b] = (m + __logf(ssum)) - realv;
  }
}

__global__ __launch_bounds__(64) void final_sum_k(const float* __restrict__ part, float* __restrict__ out) {
  float v = part[threadIdx.x];
#pragma unroll
  for (int off = 32; off > 0; off >>= 1) v += __shfl_down(v, off);
  if (threadIdx.x == 0) out[0] = v;
}

extern "C" void kernel_launch(void* const* d_in, const int* in_sizes, int n_in,
                              void* d_out, int out_size, void* d_ws, size_t ws_size,
                              hipStream_t stream) {
  const int* sent = (const int*)d_in[0];
  const int* bush = (const int*)d_in[1];
  const float* pin = (const float*)d_in[2];
  const float* wz = (const float*)d_in[3];
  const float* twz = (const float*)d_in[4];
  const int* tags = (const int*)d_in[5];
  const int* lens = (const int*)d_in[6];
  const float* emb1 = (const float*)d_in[7];
  const float* emb2 = (const float*)d_in[8];
  const float* Wq = (const float*)d_in[9];  const float* bq = (const float*)d_in[10];
  const float* Wk = (const float*)d_in[11]; const float* bk = (const float*)d_in[12];
  const float* Wv = (const float*)d_in[13]; const float* bv = (const float*)d_in[14];
  const float* Wo = (const float*)d_in[15]; const float* bo = (const float*)d_in[16];
  const float* Wihf = (const float*)d_in[17]; const float* Whhf = (const float*)d_in[18];
  const float* bihf = (const float*)d_in[19]; const float* bhhf = (const float*)d_in[20];
  const float* Wihb = (const float*)d_in[21]; const float* Whhb = (const float*)d_in[22];
  const float* bihb = (const float*)d_in[23]; const float* bhhb = (const float*)d_in[24];
  const float* Wout = (const float*)d_in[25]; const float* bout = (const float*)d_in[26];
  const float* trans = (const float*)d_in[27];
  const float* h0 = (const float*)d_in[28]; const float* c0 = (const float*)d_in[29];
  float* out = (float*)d_out;
  float* w = (float*)d_ws;
  const size_t F = (size_t)ROWSc * DMc;  // 4194304 floats
  ushort* finb = (ushort*)w;                 // [0, F/2): 16384x256 bf16
  ushort* axb  = (ushort*)w;                 // reuse after QKV GEMM
  float*  qkv  = w + F / 2;                  // [F/2, F/2+3F): 16384x768 f32
  ushort* xob  = (ushort*)(w + F / 2);       // reuse qkv region after attn
  ushort* gxb  = (ushort*)(w + F);           // [F, 3F): 16384x1024 bf16
  ushort* lout = (ushort*)(w + 3 * F);       // 16384x256 bf16
  float*  lgts = w + 4 * F;                  // 16384x20
  size_t off = 4 * F + (size_t)ROWSc * NTc;
  ushort* wqkvb = (ushort*)(w + off); off += 768 * 256 / 2;
  ushort* wihbf = (ushort*)(w + off); off += 1024 * 256 / 2;
  ushort* wob   = (ushort*)(w + off); off += 256 * 256 / 2;
  ushort* whhp  = (ushort*)(w + off); off += 2 * 512 * 128 / 2;
  float* bqkv = w + off; off += 768;
  float* bihp = w + off; off += 1024;
  float* partv = w + off;

  build_fin_k<<<ROWSc, 256, 0, stream>>>(sent, bush, pin, wz, twz, emb1, emb2, finb);
  pack_weights_k<<<256, 256, 0, stream>>>(Wq, Wk, Wv, Wo, Wihf, Wihb, bq, bk, bv, bihf, bihb,
                                          wqkvb, wihbf, wob, bqkv, bihp);
  pack_whh_k<<<64, 256, 0, stream>>>(Whhf, Whhb, whhp);
  mfma_gemm_k<768, false><<<dim3(128, 6), 256, 0, stream>>>(finb, wqkvb, bqkv, qkv);
  attn_k<<<Bc * 4 * 2, 256, 0, stream>>>(qkv, axb);
  mfma_gemm_k<256, true><<<dim3(128, 2), 256, 0, stream>>>(axb, wob, bo, xob);
  mfma_gemm_k<1024, true><<<dim3(128, 8), 256, 0, stream>>>(xob, wihbf, bihp, gxb);
  lstm_mfma_k<<<dim3(4, 2), 512, 0, stream>>>(gxb, whhp, bhhf, bhhb, h0, c0, lout);
  logits_k<<<ROWSc, 256, 0, stream>>>(lout, Wout, bout, lgts);
  crf_fwd_k<<<Bc, 64, 0, stream>>>(lgts, tags, lens, trans, partv);
  final_sum_k<<<1, 64, 0, stream>>>(partv, out);
}

// Round 6
// 863.243 us; speedup vs baseline: 1.0649x; 1.0649x over previous
//
#include <hip/hip_runtime.h>
#include <math.h>

namespace {
constexpr int Bc = 64, Lc = 256, DMc = 256;
constexpr int NTc = 20, START_c = 18, STOP_c = 19;
constexpr int ROWSc = Bc * Lc;  // 16384
}

typedef short short8 __attribute__((ext_vector_type(8)));
typedef float f32x4 __attribute__((ext_vector_type(4)));
typedef ushort ushort4v __attribute__((ext_vector_type(4)));

__device__ __forceinline__ ushort f2bf(float x) {
  unsigned u = __float_as_uint(x);
  unsigned r = (u + 0x7FFFu + ((u >> 16) & 1u)) >> 16;
  return (ushort)r;
}
__device__ __forceinline__ float bf2f(ushort h) {
  return __uint_as_float((unsigned)h << 16);
}
__device__ __forceinline__ float fast_sig(float x) {
  return __fdividef(1.f, 1.f + __expf(-x));
}
__device__ __forceinline__ float fast_tanh(float x) {
  return 1.f - __fdividef(2.f, 1.f + __expf(2.f * x));
}
// LDS-only barrier: no vmcnt(0) drain (out-stores / prefetch loads stay in flight).
__device__ __forceinline__ void lds_barrier() {
  asm volatile("s_waitcnt lgkmcnt(0)" ::: "memory");
  __builtin_amdgcn_s_barrier();
  asm volatile("" ::: "memory");
}

// ---------------- fin (bf16) = concat(emb1[sent], emb2[bush], pinyin, trans_weizhi, weizhi) ----------------
__global__ __launch_bounds__(256) void build_fin_k(
    const int* __restrict__ sent, const int* __restrict__ bush,
    const float* __restrict__ pin, const float* __restrict__ wz,
    const float* __restrict__ twz, const float* __restrict__ emb1,
    const float* __restrict__ emb2, ushort* __restrict__ finb) {
  const int row = blockIdx.x;
  const int c = threadIdx.x;
  float v;
  if (c < 100)      v = emb1[(size_t)sent[row] * 100 + c];
  else if (c < 200) v = emb2[(size_t)bush[row] * 100 + (c - 100)];
  else if (c < 220) v = pin[(size_t)row * 20 + (c - 200)];
  else if (c < 238) v = twz[(size_t)row * 18 + (c - 220)];
  else              v = wz[(size_t)row * 18 + (c - 238)];
  finb[(size_t)row * 256 + c] = f2bf(v);
}

// ---------------- pack weights/biases to bf16 ----------------
__global__ __launch_bounds__(256) void pack_weights_k(
    const float* __restrict__ Wq, const float* __restrict__ Wk,
    const float* __restrict__ Wv, const float* __restrict__ Wo,
    const float* __restrict__ Wihf, const float* __restrict__ Wihb,
    const float* __restrict__ bq, const float* __restrict__ bk,
    const float* __restrict__ bv, const float* __restrict__ bihf,
    const float* __restrict__ bihb,
    ushort* __restrict__ wqkv, ushort* __restrict__ wih, ushort* __restrict__ wo,
    float* __restrict__ bqkv, float* __restrict__ bih) {
  const int gid = blockIdx.x * 256 + threadIdx.x;  // 65536 threads
  const int row = gid >> 5;
  const int cl = (gid & 31) * 8;
  const float* src;
  ushort* dst;
  if (row < 768) {
    src = (row < 256 ? Wq : (row < 512 ? Wk : Wv)) + (size_t)(row & 255) * 256;
    dst = wqkv + (size_t)row * 256;
  } else if (row < 1792) {
    const int rr = row - 768;
    src = (rr < 512 ? Wihf + (size_t)rr * 256 : Wihb + (size_t)(rr - 512) * 256);
    dst = wih + (size_t)rr * 256;
  } else {
    const int rr = row - 1792;
    src = Wo + (size_t)rr * 256;
    dst = wo + (size_t)rr * 256;
  }
  float4 v0 = *(const float4*)(src + cl);
  float4 v1 = *(const float4*)(src + cl + 4);
  short8 o;
  o[0] = (short)f2bf(v0.x); o[1] = (short)f2bf(v0.y); o[2] = (short)f2bf(v0.z); o[3] = (short)f2bf(v0.w);
  o[4] = (short)f2bf(v1.x); o[5] = (short)f2bf(v1.y); o[6] = (short)f2bf(v1.z); o[7] = (short)f2bf(v1.w);
  *(short8*)(dst + cl) = o;
  if (gid < 768) {
    bqkv[gid] = (gid < 256 ? bq[gid] : (gid < 512 ? bk[gid - 256] : bv[gid - 512]));
  } else if (gid < 1792) {
    bih[gid - 768] = (gid < 1280 ? bihf[gid - 768] : bihb[gid - 1280]);
  }
}

// ---------------- pack Whh (2x512x128) to bf16 ----------------
__global__ __launch_bounds__(256) void pack_whh_k(
    const float* __restrict__ Whhf, const float* __restrict__ Whhb,
    ushort* __restrict__ whh) {
  const int gid = blockIdx.x * 256 + threadIdx.x;  // 16384 threads
  const int idx = gid * 8;
  const float* src = (idx < 65536) ? (Whhf + idx) : (Whhb + (idx - 65536));
  float4 v0 = *(const float4*)(src);
  float4 v1 = *(const float4*)(src + 4);
  short8 o;
  o[0] = (short)f2bf(v0.x); o[1] = (short)f2bf(v0.y); o[2] = (short)f2bf(v0.z); o[3] = (short)f2bf(v0.w);
  o[4] = (short)f2bf(v1.x); o[5] = (short)f2bf(v1.y); o[6] = (short)f2bf(v1.z); o[7] = (short)f2bf(v1.w);
  *(short8*)(whh + idx) = o;
}

// ---------------- permute Wout to [n][pc][uu] order matching louts layout ----------------
__global__ __launch_bounds__(256) void pack_wout_k(
    const float* __restrict__ Wout, float* __restrict__ woutp) {
  const int o = blockIdx.x * 256 + threadIdx.x;
  if (o >= 20 * 256) return;
  const int n = o >> 8, rest = o & 255;
  const int pc = rest >> 2, uu = rest & 3;
  const int dir = pc >> 5, w = (pc >> 2) & 7, kg = pc & 3;
  woutp[o] = Wout[n * 256 + dir * 128 + w * 16 + kg * 4 + uu];
}

// ---------------- bf16 MFMA GEMM: C[m,n] = sum_k A[m,k]*W[n,k] + bias[n]; K=256, 128x128 tile ----------------
template <int N, bool BF16_OUT>
__global__ __launch_bounds__(256, 2) void mfma_gemm_k(
    const ushort* __restrict__ A, const ushort* __restrict__ W,
    const float* __restrict__ bias, void* __restrict__ Cv) {
  const int tid = threadIdx.x, lane = tid & 63, wid = tid >> 6;
  const int bm = blockIdx.x * 128, bn = blockIdx.y * 128;
  const int wm = (wid >> 1) * 64, wn = (wid & 1) * 64;
  const int r = lane & 15, kg = lane >> 4;
  const ushort* Ap = A + (size_t)(bm + wm + r) * 256 + kg * 8;
  const ushort* Wp = W + (size_t)(bn + wn + r) * 256 + kg * 8;
  f32x4 acc[4][4];
#pragma unroll
  for (int i = 0; i < 4; ++i)
#pragma unroll
    for (int j = 0; j < 4; ++j) acc[i][j] = (f32x4){0.f, 0.f, 0.f, 0.f};
#pragma unroll
  for (int k0 = 0; k0 < 256; k0 += 32) {
    short8 a[4], b[4];
#pragma unroll
    for (int fi = 0; fi < 4; ++fi) a[fi] = *(const short8*)(Ap + fi * 16 * 256 + k0);
#pragma unroll
    for (int fj = 0; fj < 4; ++fj) b[fj] = *(const short8*)(Wp + fj * 16 * 256 + k0);
#pragma unroll
    for (int fi = 0; fi < 4; ++fi)
#pragma unroll
      for (int fj = 0; fj < 4; ++fj)
        acc[fi][fj] = __builtin_amdgcn_mfma_f32_16x16x32_bf16(a[fi], b[fj], acc[fi][fj], 0, 0, 0);
  }
#pragma unroll
  for (int fi = 0; fi < 4; ++fi)
#pragma unroll
    for (int fj = 0; fj < 4; ++fj) {
      const int n = bn + wn + fj * 16 + r;
      const float bn_ = bias[n];
#pragma unroll
      for (int rr = 0; rr < 4; ++rr) {
        const int m = bm + wm + fi * 16 + kg * 4 + rr;
        const float v = acc[fi][fj][rr] + bn_;
        if (BF16_OUT) ((ushort*)Cv)[(size_t)m * N + n] = f2bf(v);
        else          ((float*)Cv)[(size_t)m * N + n] = v;
      }
    }
}

// ---------------- transpose gx [ROWS][1024] -> gxt [s][dir][g4][b][r] (batch-innermost) ----------------
__global__ __launch_bounds__(256) void transpose_gx_k(
    const ushort* __restrict__ gx, ushort* __restrict__ gxt) {
  const int s = blockIdx.x, dir = blockIdx.y;
  const int t = threadIdx.x;
  const int b = t & 63;
  const int c = t >> 6;  // wave 0..3
  const size_t obase = (size_t)(s * 2 + dir) * 32768;
#pragma unroll 4
  for (int i = 0; i < 16; ++i) {
    const int g8 = i * 4 + c;  // 0..63
    short8 v = *(const short8*)(gx + ((size_t)b * 256 + s) * 1024 + dir * 512 + g8 * 8);
    ushort4v lo, hi;
    lo[0] = (ushort)v[0]; lo[1] = (ushort)v[1]; lo[2] = (ushort)v[2]; lo[3] = (ushort)v[3];
    hi[0] = (ushort)v[4]; hi[1] = (ushort)v[5]; hi[2] = (ushort)v[6]; hi[3] = (ushort)v[7];
    *(ushort4v*)(gxt + obase + (size_t)(g8 * 2) * 256 + b * 4) = lo;
    *(ushort4v*)(gxt + obase + (size_t)(g8 * 2 + 1) * 256 + b * 4) = hi;
  }
}

// ---------------- attention: block (b,h,qhalf); K/V staged via LDS coalesced (bf16) ----------------
__global__ __launch_bounds__(256) void attn_k(
    const float* __restrict__ qkv, ushort* __restrict__ xout) {
  const int bh = blockIdx.x >> 1, qh = blockIdx.x & 1;
  const int b = bh >> 2, h = bh & 3;
  const int tid = threadIdx.x;
  const int lane = tid & 63, w = tid >> 6;
  __shared__ __align__(16) float qs[4][64];
  __shared__ __align__(16) float pl[4][256];
  __shared__ float red[4][4];
  __shared__ float pvp[4][4][64];
  __shared__ __align__(16) ushort stg[256 * 66];  // K: [256][66]; then V: [64][258]
  const float* qb = qkv + (size_t)(b * Lc) * 768 + h * 64;
  const float* kb = qb + 256;
  const float* vb = qb + 512;
  const int srow = tid >> 2, part = tid & 3;
  // --- stage K coalesced, fill kr4 ---
#pragma unroll
  for (int pass = 0; pass < 4; ++pass) {
    const int row = pass * 64 + srow;
#pragma unroll
    for (int qq = 0; qq < 4; ++qq) {
      float4 f = *(const float4*)(kb + (size_t)row * 768 + qq * 16 + part * 4);
      ushort4v u;
      u[0] = f2bf(f.x); u[1] = f2bf(f.y); u[2] = f2bf(f.z); u[3] = f2bf(f.w);
      *(ushort4v*)(stg + row * 66 + qq * 16 + part * 4) = u;
    }
  }
  __syncthreads();
  float4 kr4[16];
#pragma unroll
  for (int j = 0; j < 16; ++j) {
    ushort4v u = *(const ushort4v*)(stg + tid * 66 + j * 4);
    kr4[j] = make_float4(bf2f(u[0]), bf2f(u[1]), bf2f(u[2]), bf2f(u[3]));
  }
  __syncthreads();
  // --- stage V transposed [d][key], fill vr4 ---
#pragma unroll
  for (int pass = 0; pass < 4; ++pass) {
    const int row = pass * 64 + srow;
#pragma unroll
    for (int qq = 0; qq < 4; ++qq) {
      float4 f = *(const float4*)(vb + (size_t)row * 768 + qq * 16 + part * 4);
      const int d0 = qq * 16 + part * 4;
      stg[(d0 + 0) * 258 + row] = f2bf(f.x);
      stg[(d0 + 1) * 258 + row] = f2bf(f.y);
      stg[(d0 + 2) * 258 + row] = f2bf(f.z);
      stg[(d0 + 3) * 258 + row] = f2bf(f.w);
    }
  }
  __syncthreads();
  float4 vr4[16];
#pragma unroll
  for (int j4 = 0; j4 < 16; ++j4) {
    ushort4v u = *(const ushort4v*)(stg + lane * 258 + w * 64 + j4 * 4);
    vr4[j4] = make_float4(bf2f(u[0]), bf2f(u[1]), bf2f(u[2]), bf2f(u[3]));
  }

  for (int q0 = qh * 128; q0 < qh * 128 + 128; q0 += 4) {
    lds_barrier();
    qs[w][lane] = qb[(size_t)(q0 + w) * 768 + lane];
    lds_barrier();
    float s0 = 0, s1 = 0, s2 = 0, s3 = 0;
#pragma unroll
    for (int d4 = 0; d4 < 16; ++d4) {
      float4 kv = kr4[d4];
      float4 q0v = *(const float4*)(&qs[0][d4 * 4]);
      float4 q1v = *(const float4*)(&qs[1][d4 * 4]);
      float4 q2v = *(const float4*)(&qs[2][d4 * 4]);
      float4 q3v = *(const float4*)(&qs[3][d4 * 4]);
      s0 += kv.x * q0v.x + kv.y * q0v.y + kv.z * q0v.z + kv.w * q0v.w;
      s1 += kv.x * q1v.x + kv.y * q1v.y + kv.z * q1v.z + kv.w * q1v.w;
      s2 += kv.x * q2v.x + kv.y * q2v.y + kv.z * q2v.z + kv.w * q2v.w;
      s3 += kv.x * q3v.x + kv.y * q3v.y + kv.z * q3v.z + kv.w * q3v.w;
    }
    s0 *= 0.125f; s1 *= 0.125f; s2 *= 0.125f; s3 *= 0.125f;
    float m0 = s0, m1 = s1, m2 = s2, m3 = s3;
#pragma unroll
    for (int off = 32; off > 0; off >>= 1) {
      m0 = fmaxf(m0, __shfl_xor(m0, off));
      m1 = fmaxf(m1, __shfl_xor(m1, off));
      m2 = fmaxf(m2, __shfl_xor(m2, off));
      m3 = fmaxf(m3, __shfl_xor(m3, off));
    }
    if (lane == 0) { red[w][0] = m0; red[w][1] = m1; red[w][2] = m2; red[w][3] = m3; }
    lds_barrier();
    const float M0 = fmaxf(fmaxf(red[0][0], red[1][0]), fmaxf(red[2][0], red[3][0]));
    const float M1 = fmaxf(fmaxf(red[0][1], red[1][1]), fmaxf(red[2][1], red[3][1]));
    const float M2 = fmaxf(fmaxf(red[0][2], red[1][2]), fmaxf(red[2][2], red[3][2]));
    const float M3 = fmaxf(fmaxf(red[0][3], red[1][3]), fmaxf(red[2][3], red[3][3]));
    const float e0 = __expf(s0 - M0), e1 = __expf(s1 - M1), e2 = __expf(s2 - M2), e3 = __expf(s3 - M3);
    pl[0][tid] = e0; pl[1][tid] = e1; pl[2][tid] = e2; pl[3][tid] = e3;
    float t0 = e0, t1 = e1, t2 = e2, t3 = e3;
#pragma unroll
    for (int off = 32; off > 0; off >>= 1) {
      t0 += __shfl_xor(t0, off); t1 += __shfl_xor(t1, off);
      t2 += __shfl_xor(t2, off); t3 += __shfl_xor(t3, off);
    }
    lds_barrier();
    if (lane == 0) { red[w][0] = t0; red[w][1] = t1; red[w][2] = t2; red[w][3] = t3; }
    lds_barrier();
    float a0 = 0, a1 = 0, a2 = 0, a3 = 0;
#pragma unroll
    for (int j4 = 0; j4 < 16; ++j4) {
      float4 vv = vr4[j4];
      float4 p0 = *(const float4*)(&pl[0][w * 64 + j4 * 4]);
      float4 p1 = *(const float4*)(&pl[1][w * 64 + j4 * 4]);
      float4 p2 = *(const float4*)(&pl[2][w * 64 + j4 * 4]);
      float4 p3 = *(const float4*)(&pl[3][w * 64 + j4 * 4]);
      a0 += p0.x * vv.x + p0.y * vv.y + p0.z * vv.z + p0.w * vv.w;
      a1 += p1.x * vv.x + p1.y * vv.y + p1.z * vv.z + p1.w * vv.w;
      a2 += p2.x * vv.x + p2.y * vv.y + p2.z * vv.z + p2.w * vv.w;
      a3 += p3.x * vv.x + p3.y * vv.y + p3.z * vv.z + p3.w * vv.w;
    }
    pvp[w][0][lane] = a0; pvp[w][1][lane] = a1; pvp[w][2][lane] = a2; pvp[w][3][lane] = a3;
    lds_barrier();
    const float den = red[0][w] + red[1][w] + red[2][w] + red[3][w];
    const float rres = (pvp[0][w][lane] + pvp[1][w][lane] + pvp[2][w][lane] + pvp[3][w][lane]) / den;
    xout[((size_t)b * Lc + q0 + w) * 256 + h * 64 + lane] = f2bf(rres);
  }
}

// ---------------- MFMA BiLSTM with coalesced gxt loads and louts stores ----------------
// gxt: [s][dir][g4][b 64][r 4]; louts: [s][dir][w 8][kg 4][b 64][uu 4]
__global__ __launch_bounds__(512, 2) void lstm_mfma_k(
    const ushort* __restrict__ gxt, const ushort* __restrict__ whh,
    const float* __restrict__ bhhf, const float* __restrict__ bhhb,
    const float* __restrict__ h0, const float* __restrict__ c0,
    ushort* __restrict__ louts) {
  const int bs = blockIdx.x * 16;
  const int dir = blockIdx.y;
  const int tid = threadIdx.x;
  const int w = tid >> 6, lane = tid & 63;
  const int col = lane & 15;  // batch within slice
  const int kg = lane >> 4;   // 0..3
  short8 afrag[4][4];
#pragma unroll
  for (int g = 0; g < 4; ++g)
#pragma unroll
    for (int ks = 0; ks < 4; ++ks)
      afrag[g][ks] = *(const short8*)(whh + (size_t)dir * 65536 +
                                      (size_t)(g * 128 + w * 16 + col) * 128 + ks * 32 + kg * 8);
  const float* bhh = dir ? bhhb : bhhf;
  float4 bias4[4];
#pragma unroll
  for (int g = 0; g < 4; ++g) bias4[g] = *(const float4*)(bhh + g * 128 + w * 16 + kg * 4);
  float4 c4 = *(const float4*)(c0 + (size_t)(dir * Bc + bs + col) * 128 + w * 16 + kg * 4);
  __shared__ __align__(16) ushort hlds[2][2048];
  {
    float4 h4 = *(const float4*)(h0 + (size_t)(dir * Bc + bs + col) * 128 + w * 16 + kg * 4);
    ushort4v hp;
    hp[0] = f2bf(h4.x); hp[1] = f2bf(h4.y); hp[2] = f2bf(h4.z); hp[3] = f2bf(h4.w);
    const int wb = (col * 256 + w * 32 + kg * 8) ^ ((col & 7) << 4);
    *(ushort4v*)((char*)hlds[0] + wb) = hp;
  }
  // thread-base into gxt: slab (s*2+dir)*32768, element (g*32+w*4+kg)*256 + (bs+col)*4
  const ushort* gtb = gxt + (size_t)dir * 32768 + (size_t)(w * 4 + kg) * 256 + (size_t)(bs + col) * 4;
  int step = dir ? (Lc - 1) : 0;
  const int dstep = dir ? -1 : 1;
  ushort4v gA[4], gB[4];
#pragma unroll
  for (int g = 0; g < 4; ++g) gA[g] = *(const ushort4v*)(gtb + (size_t)step * 65536 + g * 8192);
#pragma unroll
  for (int g = 0; g < 4; ++g) gB[g] = *(const ushort4v*)(gtb + (size_t)(step + dstep) * 65536 + g * 8192);
  __syncthreads();
  int p = 0;

  auto body = [&](ushort4v (&gcur)[4], int pfstep, bool pfok) {
    short8 bfrag[4];
#pragma unroll
    for (int ks = 0; ks < 4; ++ks) {
      const int rb = (col * 256 + ks * 64 + kg * 16) ^ ((col & 7) << 4);
      bfrag[ks] = *(const short8*)((const char*)hlds[p] + rb);
    }
    ushort4v gxc[4];
#pragma unroll
    for (int g = 0; g < 4; ++g) gxc[g] = gcur[g];
    if (pfok) {
#pragma unroll
      for (int g = 0; g < 4; ++g) gcur[g] = *(const ushort4v*)(gtb + (size_t)pfstep * 65536 + g * 8192);
    }
    f32x4 acc[4];
#pragma unroll
    for (int g = 0; g < 4; ++g) acc[g] = (f32x4){0.f, 0.f, 0.f, 0.f};
#pragma unroll
    for (int ks = 0; ks < 4; ++ks)
#pragma unroll
      for (int g = 0; g < 4; ++g)
        acc[g] = __builtin_amdgcn_mfma_f32_16x16x32_bf16(afrag[g][ks], bfrag[ks], acc[g], 0, 0, 0);
    ushort4v hp;
#pragma unroll
    for (int r = 0; r < 4; ++r) {
      const float ii = fast_sig (acc[0][r] + bf2f(gxc[0][r]) + bias4[0][r]);
      const float ff = fast_sig (acc[1][r] + bf2f(gxc[1][r]) + bias4[1][r]);
      const float gg = fast_tanh(acc[2][r] + bf2f(gxc[2][r]) + bias4[2][r]);
      const float oo = fast_sig (acc[3][r] + bf2f(gxc[3][r]) + bias4[3][r]);
      const float cn = ff * c4[r] + ii * gg;
      c4[r] = cn;
      hp[r] = f2bf(oo * fast_tanh(cn));
    }
    const int wb = (col * 256 + w * 32 + kg * 8) ^ ((col & 7) << 4);
    *(ushort4v*)((char*)hlds[p ^ 1] + wb) = hp;
    *(ushort4v*)(louts + (size_t)step * 16384 + dir * 8192 + w * 1024 + kg * 256 +
                 (size_t)(bs + col) * 4) = hp;
    asm volatile("s_waitcnt lgkmcnt(0)" ::: "memory");
    __builtin_amdgcn_s_barrier();
    asm volatile("" ::: "memory");
    p ^= 1;
    step += dstep;
  };

  for (int s = 0; s < Lc; s += 2) {
    const int pf1 = step + 2 * dstep;
    body(gA, pf1, s + 2 < Lc);
    const int pf2 = step + 2 * dstep;
    body(gB, pf2, s + 3 < Lc);
  }
}

// ---------------- logits: block per step s; stage louts slab + permuted Wout in LDS ----------------
__global__ __launch_bounds__(256) void logits_k(
    const ushort* __restrict__ louts, const float* __restrict__ woutp,
    const float* __restrict__ bout, float* __restrict__ lg) {
  const int s = blockIdx.x;
  const int t = threadIdx.x;
  __shared__ __align__(16) ushort xs[16384];
  __shared__ float wls[20 * 256];
  __shared__ float bls[20];
  {
    const ushort* src = louts + (size_t)s * 16384;
#pragma unroll
    for (int i = 0; i < 8; ++i)
      *(short8*)(xs + i * 2048 + t * 8) = *(const short8*)(src + i * 2048 + t * 8);
    for (int i = t; i < 20 * 256; i += 256) wls[i] = woutp[i];
    if (t < 20) bls[t] = bout[t];
  }
  __syncthreads();
  const int b = t & 63, tg = t >> 6;  // tags tg*5..tg*5+4
  float acc[5] = {0.f, 0.f, 0.f, 0.f, 0.f};
  for (int pc = 0; pc < 64; ++pc) {
    ushort4v x4 = *(const ushort4v*)(xs + pc * 256 + b * 4);
    const float x0 = bf2f(x4[0]), x1 = bf2f(x4[1]), x2 = bf2f(x4[2]), x3 = bf2f(x4[3]);
#pragma unroll
    for (int n = 0; n < 5; ++n) {
      const float* w4 = wls + (tg * 5 + n) * 256 + pc * 4;
      acc[n] += x0 * w4[0] + x1 * w4[1] + x2 * w4[2] + x3 * w4[3];
    }
  }
#pragma unroll
  for (int n = 0; n < 5; ++n)
    lg[((size_t)b * Lc + s) * NTc + tg * 5 + n] = acc[n] + bls[tg * 5 + n];
}

// ---------------- CRF: gold score + forward logsumexp scan; writes total - real ----------------
__global__ __launch_bounds__(64) void crf_fwd_k(
    const float* __restrict__ lg, const int* __restrict__ tags,
    const int* __restrict__ lens, const float* __restrict__ tr,
    float* __restrict__ part) {
  const int b = blockIdx.x, j = threadIdx.x;
  __shared__ float prev[NTc];
  __shared__ float tl[NTc * NTc];
  if (j < NTc) prev[j] = 0.f;
  for (int i = j; i < NTc * NTc; i += 64) tl[i] = tr[i];
  __syncthreads();
  const int len = lens[b];
  float gv = 0.f;
  for (int t = j; t < len; t += 64) {
    const int tag = tags[b * Lc + t];
    const int pv = (t == 0) ? START_c : tags[b * Lc + t - 1];
    gv += lg[((size_t)b * Lc + t) * NTc + tag] + tl[pv * NTc + tag];
  }
#pragma unroll
  for (int off = 32; off > 0; off >>= 1) gv += __shfl_xor(gv, off);
  float trc[NTc];
  if (j < NTc) {
#pragma unroll
    for (int i = 0; i < NTc; ++i) trc[i] = tl[i * NTc + j];
  }
  float lgn = (j < NTc) ? lg[((size_t)b * Lc) * NTc + j] : 0.f;
  for (int t = 0; t < len; ++t) {
    const float lgc = lgn;
    float nj = 0.f;
    if (j < NTc) {
      if (t + 1 < len) lgn = lg[((size_t)b * Lc + t + 1) * NTc + j];
      float v[NTc];
      float m = -1e30f;
#pragma unroll
      for (int i = 0; i < NTc; ++i) { v[i] = prev[i] + trc[i]; m = fmaxf(m, v[i]); }
      float ssum = 0.f;
#pragma unroll
      for (int i = 0; i < NTc; ++i) ssum += __expf(v[i] - m);
      nj = m + __logf(ssum) + lgc;
    }
    __syncthreads();
    if (j < NTc) prev[j] = nj;
    __syncthreads();
  }
  if (j == 0) {
    const int lt = tags[b * Lc + len - 1];
    const float realv = gv + tl[lt * NTc + STOP_c];
    float m = -1e30f;
#pragma unroll
    for (int i = 0; i < NTc; ++i) m = fmaxf(m, prev[i] + tl[i * NTc + STOP_c]);
    float ssum = 0.f;
#pragma unroll
    for (int i = 0; i < NTc; ++i) ssum += __expf(prev[i] + tl[i * NTc + STOP_c] - m);
    part[b] = (m + __logf(ssum)) - realv;
  }
}

__global__ __launch_bounds__(64) void final_sum_k(const float* __restrict__ part, float* __restrict__ out) {
  float v = part[threadIdx.x];
#pragma unroll
  for (int off = 32; off > 0; off >>= 1) v += __shfl_down(v, off);
  if (threadIdx.x == 0) out[0] = v;
}

extern "C" void kernel_launch(void* const* d_in, const int* in_sizes, int n_in,
                              void* d_out, int out_size, void* d_ws, size_t ws_size,
                              hipStream_t stream) {
  const int* sent = (const int*)d_in[0];
  const int* bush = (const int*)d_in[1];
  const float* pin = (const float*)d_in[2];
  const float* wz = (const float*)d_in[3];
  const float* twz = (const float*)d_in[4];
  const int* tags = (const int*)d_in[5];
  const int* lens = (const int*)d_in[6];
  const float* emb1 = (const float*)d_in[7];
  const float* emb2 = (const float*)d_in[8];
  const float* Wq = (const float*)d_in[9];  const float* bq = (const float*)d_in[10];
  const float* Wk = (const float*)d_in[11]; const float* bk = (const float*)d_in[12];
  const float* Wv = (const float*)d_in[13]; const float* bv = (const float*)d_in[14];
  const float* Wo = (const float*)d_in[15]; const float* bo = (const float*)d_in[16];
  const float* Wihf = (const float*)d_in[17]; const float* Whhf = (const float*)d_in[18];
  const float* bihf = (const float*)d_in[19]; const float* bhhf = (const float*)d_in[20];
  const float* Wihb = (const float*)d_in[21]; const float* Whhb = (const float*)d_in[22];
  const float* bihb = (const float*)d_in[23]; const float* bhhb = (const float*)d_in[24];
  const float* Wout = (const float*)d_in[25]; const float* bout = (const float*)d_in[26];
  const float* trans = (const float*)d_in[27];
  const float* h0 = (const float*)d_in[28]; const float* c0 = (const float*)d_in[29];
  float* out = (float*)d_out;
  float* w = (float*)d_ws;
  const size_t F = (size_t)ROWSc * DMc;  // 4194304 floats
  // Arena (floats): [0,0.5F) finb/axb | [0.5F,3.5F) qkv (f32) then xob head, later gxt at [1.5F,3.5F)
  //                 [3.5F,5.5F) gx row-major, later louts | [5.5F..) lgts + weights. ~94 MB total.
  ushort* finb = (ushort*)w;
  ushort* axb  = (ushort*)w;
  float*  qkv  = w + F / 2;
  ushort* xob  = (ushort*)(w + F / 2);
  ushort* gxt  = (ushort*)(w + F + F / 2);
  ushort* gxb  = (ushort*)(w + 3 * F + F / 2);
  ushort* louts = (ushort*)(w + 3 * F + F / 2);
  float*  lgts = w + 5 * F + F / 2;
  size_t off = 5 * F + F / 2 + (size_t)ROWSc * NTc;
  ushort* wqkvb = (ushort*)(w + off); off += 768 * 256 / 2;
  ushort* wihbf = (ushort*)(w + off); off += 1024 * 256 / 2;
  ushort* wob   = (ushort*)(w + off); off += 256 * 256 / 2;
  ushort* whhp  = (ushort*)(w + off); off += 2 * 512 * 128 / 2;
  float* woutp = w + off; off += 20 * 256;
  float* bqkv = w + off; off += 768;
  float* bihp = w + off; off += 1024;
  float* partv = w + off;

  build_fin_k<<<ROWSc, 256, 0, stream>>>(sent, bush, pin, wz, twz, emb1, emb2, finb);
  pack_weights_k<<<256, 256, 0, stream>>>(Wq, Wk, Wv, Wo, Wihf, Wihb, bq, bk, bv, bihf, bihb,
                                          wqkvb, wihbf, wob, bqkv, bihp);
  pack_whh_k<<<64, 256, 0, stream>>>(Whhf, Whhb, whhp);
  pack_wout_k<<<20, 256, 0, stream>>>(Wout, woutp);
  mfma_gemm_k<768, false><<<dim3(128, 6), 256, 0, stream>>>(finb, wqkvb, bqkv, qkv);
  attn_k<<<Bc * 4 * 2, 256, 0, stream>>>(qkv, axb);
  mfma_gemm_k<256, true><<<dim3(128, 2), 256, 0, stream>>>(axb, wob, bo, xob);
  mfma_gemm_k<1024, true><<<dim3(128, 8), 256, 0, stream>>>(xob, wihbf, bihp, gxb);
  transpose_gx_k<<<dim3(256, 2), 256, 0, stream>>>(gxb, gxt);
  lstm_mfma_k<<<dim3(4, 2), 512, 0, stream>>>(gxt, whhp, bhhf, bhhb, h0, c0, louts);
  logits_k<<<Lc, 256, 0, stream>>>(louts, woutp, bout, lgts);
  crf_fwd_k<<<Bc, 64, 0, stream>>>(lgts, tags, lens, trans, partv);
  final_sum_k<<<1, 64, 0, stream>>>(partv, out);
}

// Round 7
// 650.304 us; speedup vs baseline: 1.4136x; 1.3274x over previous
//
#include <hip/hip_runtime.h>
#include <math.h>

namespace {
constexpr int Bc = 64, Lc = 256, DMc = 256;
constexpr int NTc = 20, START_c = 18, STOP_c = 19;
constexpr int ROWSc = Bc * Lc;  // 16384
}

typedef short short8 __attribute__((ext_vector_type(8)));
typedef float f32x4 __attribute__((ext_vector_type(4)));
typedef ushort ushort4v __attribute__((ext_vector_type(4)));

__device__ __forceinline__ ushort f2bf(float x) {
  unsigned u = __float_as_uint(x);
  unsigned r = (u + 0x7FFFu + ((u >> 16) & 1u)) >> 16;
  return (ushort)r;
}
__device__ __forceinline__ float bf2f(ushort h) {
  return __uint_as_float((unsigned)h << 16);
}
// raw v_rcp_f32: ~1ulp, 1 instr (vs __fdividef's full IEEE div expansion)
__device__ __forceinline__ float vrcp(float x) {
  float r;
  asm("v_rcp_f32 %0, %1" : "=v"(r) : "v"(x));
  return r;
}
__device__ __forceinline__ float fast_sig(float x) {
  return vrcp(1.f + __expf(-x));
}
__device__ __forceinline__ float fast_tanh(float x) {
  return fmaf(-2.f, vrcp(1.f + __expf(2.f * x)), 1.f);
}
// pack 2 f32 -> 2 bf16 (RNE) in one instr
__device__ __forceinline__ unsigned cvtpk(float a, float b) {
  unsigned r;
  asm("v_cvt_pk_bf16_f32 %0, %1, %2" : "=v"(r) : "v"(a), "v"(b));
  return r;
}
// LDS-only barrier: no vmcnt(0) drain (out-stores / prefetch loads stay in flight).
__device__ __forceinline__ void lds_barrier() {
  asm volatile("s_waitcnt lgkmcnt(0)" ::: "memory");
  __builtin_amdgcn_s_barrier();
  asm volatile("" ::: "memory");
}

// ---------------- fin (bf16) = concat(emb1[sent], emb2[bush], pinyin, trans_weizhi, weizhi) ----------------
__global__ __launch_bounds__(256) void build_fin_k(
    const int* __restrict__ sent, const int* __restrict__ bush,
    const float* __restrict__ pin, const float* __restrict__ wz,
    const float* __restrict__ twz, const float* __restrict__ emb1,
    const float* __restrict__ emb2, ushort* __restrict__ finb) {
  const int row = blockIdx.x;
  const int c = threadIdx.x;
  float v;
  if (c < 100)      v = emb1[(size_t)sent[row] * 100 + c];
  else if (c < 200) v = emb2[(size_t)bush[row] * 100 + (c - 100)];
  else if (c < 220) v = pin[(size_t)row * 20 + (c - 200)];
  else if (c < 238) v = twz[(size_t)row * 18 + (c - 220)];
  else              v = wz[(size_t)row * 18 + (c - 238)];
  finb[(size_t)row * 256 + c] = f2bf(v);
}

// ---------------- pack weights/biases to bf16 ----------------
__global__ __launch_bounds__(256) void pack_weights_k(
    const float* __restrict__ Wq, const float* __restrict__ Wk,
    const float* __restrict__ Wv, const float* __restrict__ Wo,
    const float* __restrict__ Wihf, const float* __restrict__ Wihb,
    const float* __restrict__ bq, const float* __restrict__ bk,
    const float* __restrict__ bv, const float* __restrict__ bihf,
    const float* __restrict__ bihb,
    ushort* __restrict__ wqkv, ushort* __restrict__ wih, ushort* __restrict__ wo,
    float* __restrict__ bqkv, float* __restrict__ bih) {
  const int gid = blockIdx.x * 256 + threadIdx.x;  // 65536 threads
  const int row = gid >> 5;
  const int cl = (gid & 31) * 8;
  const float* src;
  ushort* dst;
  if (row < 768) {
    src = (row < 256 ? Wq : (row < 512 ? Wk : Wv)) + (size_t)(row & 255) * 256;
    dst = wqkv + (size_t)row * 256;
  } else if (row < 1792) {
    const int rr = row - 768;
    src = (rr < 512 ? Wihf + (size_t)rr * 256 : Wihb + (size_t)(rr - 512) * 256);
    dst = wih + (size_t)rr * 256;
  } else {
    const int rr = row - 1792;
    src = Wo + (size_t)rr * 256;
    dst = wo + (size_t)rr * 256;
  }
  float4 v0 = *(const float4*)(src + cl);
  float4 v1 = *(const float4*)(src + cl + 4);
  short8 o;
  o[0] = (short)f2bf(v0.x); o[1] = (short)f2bf(v0.y); o[2] = (short)f2bf(v0.z); o[3] = (short)f2bf(v0.w);
  o[4] = (short)f2bf(v1.x); o[5] = (short)f2bf(v1.y); o[6] = (short)f2bf(v1.z); o[7] = (short)f2bf(v1.w);
  *(short8*)(dst + cl) = o;
  if (gid < 768) {
    bqkv[gid] = (gid < 256 ? bq[gid] : (gid < 512 ? bk[gid - 256] : bv[gid - 512]));
  } else if (gid < 1792) {
    bih[gid - 768] = (gid < 1280 ? bihf[gid - 768] : bihb[gid - 1280]);
  }
}

// ---------------- pack Whh (2x512x128) to bf16 ----------------
__global__ __launch_bounds__(256) void pack_whh_k(
    const float* __restrict__ Whhf, const float* __restrict__ Whhb,
    ushort* __restrict__ whh) {
  const int gid = blockIdx.x * 256 + threadIdx.x;  // 16384 threads
  const int idx = gid * 8;
  const float* src = (idx < 65536) ? (Whhf + idx) : (Whhb + (idx - 65536));
  float4 v0 = *(const float4*)(src);
  float4 v1 = *(const float4*)(src + 4);
  short8 o;
  o[0] = (short)f2bf(v0.x); o[1] = (short)f2bf(v0.y); o[2] = (short)f2bf(v0.z); o[3] = (short)f2bf(v0.w);
  o[4] = (short)f2bf(v1.x); o[5] = (short)f2bf(v1.y); o[6] = (short)f2bf(v1.z); o[7] = (short)f2bf(v1.w);
  *(short8*)(whh + idx) = o;
}

// ---------------- permute Wout to [n][pc][uu] order matching louts layout ----------------
__global__ __launch_bounds__(256) void pack_wout_k(
    const float* __restrict__ Wout, float* __restrict__ woutp) {
  const int o = blockIdx.x * 256 + threadIdx.x;
  if (o >= 20 * 256) return;
  const int n = o >> 8, rest = o & 255;
  const int pc = rest >> 2, uu = rest & 3;
  const int dir = pc >> 5, w = (pc >> 2) & 7, kg = pc & 3;
  woutp[o] = Wout[n * 256 + dir * 128 + w * 16 + kg * 4 + uu];
}

// ---------------- bf16 MFMA GEMM: C[m,n] = sum_k A[m,k]*W[n,k] + bias[n]; K=256, 128x128 tile ----------------
template <int N, bool BF16_OUT>
__global__ __launch_bounds__(256, 2) void mfma_gemm_k(
    const ushort* __restrict__ A, const ushort* __restrict__ W,
    const float* __restrict__ bias, void* __restrict__ Cv) {
  const int tid = threadIdx.x, lane = tid & 63, wid = tid >> 6;
  const int bm = blockIdx.x * 128, bn = blockIdx.y * 128;
  const int wm = (wid >> 1) * 64, wn = (wid & 1) * 64;
  const int r = lane & 15, kg = lane >> 4;
  const ushort* Ap = A + (size_t)(bm + wm + r) * 256 + kg * 8;
  const ushort* Wp = W + (size_t)(bn + wn + r) * 256 + kg * 8;
  f32x4 acc[4][4];
#pragma unroll
  for (int i = 0; i < 4; ++i)
#pragma unroll
    for (int j = 0; j < 4; ++j) acc[i][j] = (f32x4){0.f, 0.f, 0.f, 0.f};
#pragma unroll
  for (int k0 = 0; k0 < 256; k0 += 32) {
    short8 a[4], b[4];
#pragma unroll
    for (int fi = 0; fi < 4; ++fi) a[fi] = *(const short8*)(Ap + fi * 16 * 256 + k0);
#pragma unroll
    for (int fj = 0; fj < 4; ++fj) b[fj] = *(const short8*)(Wp + fj * 16 * 256 + k0);
#pragma unroll
    for (int fi = 0; fi < 4; ++fi)
#pragma unroll
      for (int fj = 0; fj < 4; ++fj)
        acc[fi][fj] = __builtin_amdgcn_mfma_f32_16x16x32_bf16(a[fi], b[fj], acc[fi][fj], 0, 0, 0);
  }
#pragma unroll
  for (int fi = 0; fi < 4; ++fi)
#pragma unroll
    for (int fj = 0; fj < 4; ++fj) {
      const int n = bn + wn + fj * 16 + r;
      const float bn_ = bias[n];
#pragma unroll
      for (int rr = 0; rr < 4; ++rr) {
        const int m = bm + wm + fi * 16 + kg * 4 + rr;
        const float v = acc[fi][fj][rr] + bn_;
        if (BF16_OUT) ((ushort*)Cv)[(size_t)m * N + n] = f2bf(v);
        else          ((float*)Cv)[(size_t)m * N + n] = v;
      }
    }
}

// ---------------- transpose gx -> gxt [s][dir][grow][b][r], folding in bhh ----------------
__global__ __launch_bounds__(256) void transpose_gx_k(
    const ushort* __restrict__ gx, const float* __restrict__ bhhf,
    const float* __restrict__ bhhb, ushort* __restrict__ gxt) {
  const int s = blockIdx.x, dir = blockIdx.y;
  const int t = threadIdx.x;
  const int b = t & 63;
  const int c = t >> 6;  // wave 0..3
  const float* bhh = dir ? bhhb : bhhf;
  const size_t obase = (size_t)(s * 2 + dir) * 32768;
#pragma unroll 4
  for (int i = 0; i < 16; ++i) {
    const int g8 = i * 4 + c;  // 0..63
    short8 v = *(const short8*)(gx + ((size_t)b * 256 + s) * 1024 + dir * 512 + g8 * 8);
    float f[8];
#pragma unroll
    for (int j = 0; j < 8; ++j) f[j] = bf2f((ushort)v[j]) + bhh[g8 * 8 + j];
    uint2 lo = make_uint2(cvtpk(f[0], f[1]), cvtpk(f[2], f[3]));
    uint2 hi = make_uint2(cvtpk(f[4], f[5]), cvtpk(f[6], f[7]));
    *(uint2*)(gxt + obase + (size_t)(g8 * 2) * 256 + b * 4) = lo;
    *(uint2*)(gxt + obase + (size_t)(g8 * 2 + 1) * 256 + b * 4) = hi;
  }
}

// ---------------- attention: block (b,h,qhalf); K/V staged via LDS coalesced (bf16) ----------------
__global__ __launch_bounds__(256) void attn_k(
    const float* __restrict__ qkv, ushort* __restrict__ xout) {
  const int bh = blockIdx.x >> 1, qh = blockIdx.x & 1;
  const int b = bh >> 2, h = bh & 3;
  const int tid = threadIdx.x;
  const int lane = tid & 63, w = tid >> 6;
  __shared__ __align__(16) float qs[4][64];
  __shared__ __align__(16) float pl[4][256];
  __shared__ float red[4][4];
  __shared__ float pvp[4][4][64];
  __shared__ __align__(16) ushort stg[256 * 66];  // K: [256][66]; then V: [64][258]
  const float* qb = qkv + (size_t)(b * Lc) * 768 + h * 64;
  const float* kb = qb + 256;
  const float* vb = qb + 512;
  const int srow = tid >> 2, part = tid & 3;
#pragma unroll
  for (int pass = 0; pass < 4; ++pass) {
    const int row = pass * 64 + srow;
#pragma unroll
    for (int qq = 0; qq < 4; ++qq) {
      float4 f = *(const float4*)(kb + (size_t)row * 768 + qq * 16 + part * 4);
      ushort4v u;
      u[0] = f2bf(f.x); u[1] = f2bf(f.y); u[2] = f2bf(f.z); u[3] = f2bf(f.w);
      *(ushort4v*)(stg + row * 66 + qq * 16 + part * 4) = u;
    }
  }
  __syncthreads();
  float4 kr4[16];
#pragma unroll
  for (int j = 0; j < 16; ++j) {
    ushort4v u = *(const ushort4v*)(stg + tid * 66 + j * 4);
    kr4[j] = make_float4(bf2f(u[0]), bf2f(u[1]), bf2f(u[2]), bf2f(u[3]));
  }
  __syncthreads();
#pragma unroll
  for (int pass = 0; pass < 4; ++pass) {
    const int row = pass * 64 + srow;
#pragma unroll
    for (int qq = 0; qq < 4; ++qq) {
      float4 f = *(const float4*)(vb + (size_t)row * 768 + qq * 16 + part * 4);
      const int d0 = qq * 16 + part * 4;
      stg[(d0 + 0) * 258 + row] = f2bf(f.x);
      stg[(d0 + 1) * 258 + row] = f2bf(f.y);
      stg[(d0 + 2) * 258 + row] = f2bf(f.z);
      stg[(d0 + 3) * 258 + row] = f2bf(f.w);
    }
  }
  __syncthreads();
  float4 vr4[16];
#pragma unroll
  for (int j4 = 0; j4 < 16; ++j4) {
    ushort4v u = *(const ushort4v*)(stg + lane * 258 + w * 64 + j4 * 4);
    vr4[j4] = make_float4(bf2f(u[0]), bf2f(u[1]), bf2f(u[2]), bf2f(u[3]));
  }

  for (int q0 = qh * 128; q0 < qh * 128 + 128; q0 += 4) {
    lds_barrier();
    qs[w][lane] = qb[(size_t)(q0 + w) * 768 + lane];
    lds_barrier();
    float s0 = 0, s1 = 0, s2 = 0, s3 = 0;
#pragma unroll
    for (int d4 = 0; d4 < 16; ++d4) {
      float4 kv = kr4[d4];
      float4 q0v = *(const float4*)(&qs[0][d4 * 4]);
      float4 q1v = *(const float4*)(&qs[1][d4 * 4]);
      float4 q2v = *(const float4*)(&qs[2][d4 * 4]);
      float4 q3v = *(const float4*)(&qs[3][d4 * 4]);
      s0 += kv.x * q0v.x + kv.y * q0v.y + kv.z * q0v.z + kv.w * q0v.w;
      s1 += kv.x * q1v.x + kv.y * q1v.y + kv.z * q1v.z + kv.w * q1v.w;
      s2 += kv.x * q2v.x + kv.y * q2v.y + kv.z * q2v.z + kv.w * q2v.w;
      s3 += kv.x * q3v.x + kv.y * q3v.y + kv.z * q3v.z + kv.w * q3v.w;
    }
    s0 *= 0.125f; s1 *= 0.125f; s2 *= 0.125f; s3 *= 0.125f;
    float m0 = s0, m1 = s1, m2 = s2, m3 = s3;
#pragma unroll
    for (int off = 32; off > 0; off >>= 1) {
      m0 = fmaxf(m0, __shfl_xor(m0, off));
      m1 = fmaxf(m1, __shfl_xor(m1, off));
      m2 = fmaxf(m2, __shfl_xor(m2, off));
      m3 = fmaxf(m3, __shfl_xor(m3, off));
    }
    if (lane == 0) { red[w][0] = m0; red[w][1] = m1; red[w][2] = m2; red[w][3] = m3; }
    lds_barrier();
    const float M0 = fmaxf(fmaxf(red[0][0], red[1][0]), fmaxf(red[2][0], red[3][0]));
    const float M1 = fmaxf(fmaxf(red[0][1], red[1][1]), fmaxf(red[2][1], red[3][1]));
    const float M2 = fmaxf(fmaxf(red[0][2], red[1][2]), fmaxf(red[2][2], red[3][2]));
    const float M3 = fmaxf(fmaxf(red[0][3], red[1][3]), fmaxf(red[2][3], red[3][3]));
    const float e0 = __expf(s0 - M0), e1 = __expf(s1 - M1), e2 = __expf(s2 - M2), e3 = __expf(s3 - M3);
    pl[0][tid] = e0; pl[1][tid] = e1; pl[2][tid] = e2; pl[3][tid] = e3;
    float t0 = e0, t1 = e1, t2 = e2, t3 = e3;
#pragma unroll
    for (int off = 32; off > 0; off >>= 1) {
      t0 += __shfl_xor(t0, off); t1 += __shfl_xor(t1, off);
      t2 += __shfl_xor(t2, off); t3 += __shfl_xor(t3, off);
    }
    lds_barrier();
    if (lane == 0) { red[w][0] = t0; red[w][1] = t1; red[w][2] = t2; red[w][3] = t3; }
    lds_barrier();
    float a0 = 0, a1 = 0, a2 = 0, a3 = 0;
#pragma unroll
    for (int j4 = 0; j4 < 16; ++j4) {
      float4 vv = vr4[j4];
      float4 p0 = *(const float4*)(&pl[0][w * 64 + j4 * 4]);
      float4 p1 = *(const float4*)(&pl[1][w * 64 + j4 * 4]);
      float4 p2 = *(const float4*)(&pl[2][w * 64 + j4 * 4]);
      float4 p3 = *(const float4*)(&pl[3][w * 64 + j4 * 4]);
      a0 += p0.x * vv.x + p0.y * vv.y + p0.z * vv.z + p0.w * vv.w;
      a1 += p1.x * vv.x + p1.y * vv.y + p1.z * vv.z + p1.w * vv.w;
      a2 += p2.x * vv.x + p2.y * vv.y + p2.z * vv.z + p2.w * vv.w;
      a3 += p3.x * vv.x + p3.y * vv.y + p3.z * vv.z + p3.w * vv.w;
    }
    pvp[w][0][lane] = a0; pvp[w][1][lane] = a1; pvp[w][2][lane] = a2; pvp[w][3][lane] = a3;
    lds_barrier();
    const float den = red[0][w] + red[1][w] + red[2][w] + red[3][w];
    const float rres = (pvp[0][w][lane] + pvp[1][w][lane] + pvp[2][w][lane] + pvp[3][w][lane]) * vrcp(den);
    xout[((size_t)b * Lc + q0 + w) * 256 + h * 64 + lane] = f2bf(rres);
  }
}

// ---------------- MFMA BiLSTM; gx-as-C-init, rcp activations, cvt_pk packing ----------------
// gxt: [s][dir][grow 128][b 64][r 4] (bhh folded in); louts: [s][dir][w 8][kg 4][b 64][uu 4]
__global__ __launch_bounds__(512, 2) void lstm_mfma_k(
    const ushort* __restrict__ gxt, const ushort* __restrict__ whh,
    const float* __restrict__ h0, const float* __restrict__ c0,
    ushort* __restrict__ louts) {
  const int bs = blockIdx.x * 16;
  const int dir = blockIdx.y;
  const int tid = threadIdx.x;
  const int w = tid >> 6, lane = tid & 63;
  const int col = lane & 15;  // batch within slice
  const int kg = lane >> 4;   // 0..3
  short8 afrag[4][4];
#pragma unroll
  for (int g = 0; g < 4; ++g)
#pragma unroll
    for (int ks = 0; ks < 4; ++ks)
      afrag[g][ks] = *(const short8*)(whh + (size_t)dir * 65536 +
                                      (size_t)(g * 128 + w * 16 + col) * 128 + ks * 32 + kg * 8);
  float4 c4 = *(const float4*)(c0 + (size_t)(dir * Bc + bs + col) * 128 + w * 16 + kg * 4);
  __shared__ __align__(16) ushort hlds[2][2048];
  {
    float4 h4 = *(const float4*)(h0 + (size_t)(dir * Bc + bs + col) * 128 + w * 16 + kg * 4);
    const int wb = (col * 256 + w * 32 + kg * 8) ^ ((col & 7) << 4);
    *(uint2*)((char*)hlds[0] + wb) = make_uint2(cvtpk(h4.x, h4.y), cvtpk(h4.z, h4.w));
  }
  const ushort* gtb = gxt + (size_t)dir * 32768 + (size_t)(w * 4 + kg) * 256 + (size_t)(bs + col) * 4;
  int step = dir ? (Lc - 1) : 0;
  const int dstep = dir ? -1 : 1;
  ushort4v gA[4], gB[4];
#pragma unroll
  for (int g = 0; g < 4; ++g) gA[g] = *(const ushort4v*)(gtb + (size_t)step * 65536 + g * 8192);
#pragma unroll
  for (int g = 0; g < 4; ++g) gB[g] = *(const ushort4v*)(gtb + (size_t)(step + dstep) * 65536 + g * 8192);
  __syncthreads();
  int p = 0;

  auto body = [&](ushort4v (&gcur)[4], int pfstep, bool pfok) {
    short8 bfrag[4];
#pragma unroll
    for (int ks = 0; ks < 4; ++ks) {
      const int rb = (col * 256 + ks * 64 + kg * 16) ^ ((col & 7) << 4);
      bfrag[ks] = *(const short8*)((const char*)hlds[p] + rb);
    }
    // init accumulators from gate-input (gx + bih + bhh already folded)
    f32x4 acc[4];
#pragma unroll
    for (int g = 0; g < 4; ++g)
      acc[g] = (f32x4){bf2f(gcur[g][0]), bf2f(gcur[g][1]), bf2f(gcur[g][2]), bf2f(gcur[g][3])};
    if (pfok) {
#pragma unroll
      for (int g = 0; g < 4; ++g) gcur[g] = *(const ushort4v*)(gtb + (size_t)pfstep * 65536 + g * 8192);
    }
#pragma unroll
    for (int ks = 0; ks < 4; ++ks)
#pragma unroll
      for (int g = 0; g < 4; ++g)
        acc[g] = __builtin_amdgcn_mfma_f32_16x16x32_bf16(afrag[g][ks], bfrag[ks], acc[g], 0, 0, 0);
    f32x4 hr;
#pragma unroll
    for (int r = 0; r < 4; ++r) {
      const float ii = fast_sig (acc[0][r]);
      const float ff = fast_sig (acc[1][r]);
      const float gg = fast_tanh(acc[2][r]);
      const float oo = fast_sig (acc[3][r]);
      const float cn = ff * c4[r] + ii * gg;
      c4[r] = cn;
      hr[r] = oo * fast_tanh(cn);
    }
    const uint2 hp2 = make_uint2(cvtpk(hr[0], hr[1]), cvtpk(hr[2], hr[3]));
    const int wb = (col * 256 + w * 32 + kg * 8) ^ ((col & 7) << 4);
    *(uint2*)((char*)hlds[p ^ 1] + wb) = hp2;
    *(uint2*)(louts + (size_t)step * 16384 + dir * 8192 + w * 1024 + kg * 256 +
              (size_t)(bs + col) * 4) = hp2;
    asm volatile("s_waitcnt lgkmcnt(0)" ::: "memory");
    __builtin_amdgcn_s_barrier();
    asm volatile("" ::: "memory");
    p ^= 1;
    step += dstep;
  };

  for (int s = 0; s < Lc; s += 2) {
    const int pf1 = step + 2 * dstep;
    body(gA, pf1, s + 2 < Lc);
    const int pf2 = step + 2 * dstep;
    body(gB, pf2, s + 3 < Lc);
  }
}

// ---------------- logits: block per step s; stage louts slab + permuted Wout in LDS ----------------
__global__ __launch_bounds__(256) void logits_k(
    const ushort* __restrict__ louts, const float* __restrict__ woutp,
    const float* __restrict__ bout, float* __restrict__ lg) {
  const int s = blockIdx.x;
  const int t = threadIdx.x;
  __shared__ __align__(16) ushort xs[16384];
  __shared__ float wls[20 * 256];
  __shared__ float bls[20];
  {
    const ushort* src = louts + (size_t)s * 16384;
#pragma unroll
    for (int i = 0; i < 8; ++i)
      *(short8*)(xs + i * 2048 + t * 8) = *(const short8*)(src + i * 2048 + t * 8);
    for (int i = t; i < 20 * 256; i += 256) wls[i] = woutp[i];
    if (t < 20) bls[t] = bout[t];
  }
  __syncthreads();
  const int b = t & 63, tg = t >> 6;  // tags tg*5..tg*5+4
  float acc[5] = {0.f, 0.f, 0.f, 0.f, 0.f};
  for (int pc = 0; pc < 64; ++pc) {
    ushort4v x4 = *(const ushort4v*)(xs + pc * 256 + b * 4);
    const float x0 = bf2f(x4[0]), x1 = bf2f(x4[1]), x2 = bf2f(x4[2]), x3 = bf2f(x4[3]);
#pragma unroll
    for (int n = 0; n < 5; ++n) {
      const float* w4 = wls + (tg * 5 + n) * 256 + pc * 4;
      acc[n] += x0 * w4[0] + x1 * w4[1] + x2 * w4[2] + x3 * w4[3];
    }
  }
#pragma unroll
  for (int n = 0; n < 5; ++n)
    lg[((size_t)b * Lc + s) * NTc + tg * 5 + n] = acc[n] + bls[tg * 5 + n];
}

// ---------------- CRF: gold score + forward logsumexp scan; writes total - real ----------------
__global__ __launch_bounds__(64) void crf_fwd_k(
    const float* __restrict__ lg, const int* __restrict__ tags,
    const int* __restrict__ lens, const float* __restrict__ tr,
    float* __restrict__ part) {
  const int b = blockIdx.x, j = threadIdx.x;
  __shared__ float prev[NTc];
  __shared__ float tl[NTc * NTc];
  if (j < NTc) prev[j] = 0.f;
  for (int i = j; i < NTc * NTc; i += 64) tl[i] = tr[i];
  __syncthreads();
  const int len = lens[b];
  float gv = 0.f;
  for (int t = j; t < len; t += 64) {
    const int tag = tags[b * Lc + t];
    const int pv = (t == 0) ? START_c : tags[b * Lc + t - 1];
    gv += lg[((size_t)b * Lc + t) * NTc + tag] + tl[pv * NTc + tag];
  }
#pragma unroll
  for (int off = 32; off > 0; off >>= 1) gv += __shfl_xor(gv, off);
  float trc[NTc];
  if (j < NTc) {
#pragma unroll
    for (int i = 0; i < NTc; ++i) trc[i] = tl[i * NTc + j];
  }
  float lgn = (j < NTc) ? lg[((size_t)b * Lc) * NTc + j] : 0.f;
  for (int t = 0; t < len; ++t) {
    const float lgc = lgn;
    float nj = 0.f;
    if (j < NTc) {
      if (t + 1 < len) lgn = lg[((size_t)b * Lc + t + 1) * NTc + j];
      float v[NTc];
      float m = -1e30f;
#pragma unroll
      for (int i = 0; i < NTc; ++i) { v[i] = prev[i] + trc[i]; m = fmaxf(m, v[i]); }
      float ssum = 0.f;
#pragma unroll
      for (int i = 0; i < NTc; ++i) ssum += __expf(v[i] - m);
      nj = m + __logf(ssum) + lgc;
    }
    __syncthreads();
    if (j < NTc) prev[j] = nj;
    __syncthreads();
  }
  if (j == 0) {
    const int lt = tags[b * Lc + len - 1];
    const float realv = gv + tl[lt * NTc + STOP_c];
    float m = -1e30f;
#pragma unroll
    for (int i = 0; i < NTc; ++i) m = fmaxf(m, prev[i] + tl[i * NTc + STOP_c]);
    float ssum = 0.f;
#pragma unroll
    for (int i = 0; i < NTc; ++i) ssum += __expf(prev[i] + tl[i * NTc + STOP_c] - m);
    part[b] = (m + __logf(ssum)) - realv;
  }
}

__global__ __launch_bounds__(64) void final_sum_k(const float* __restrict__ part, float* __restrict__ out) {
  float v = part[threadIdx.x];
#pragma unroll
  for (int off = 32; off > 0; off >>= 1) v += __shfl_down(v, off);
  if (threadIdx.x == 0) out[0] = v;
}

extern "C" void kernel_launch(void* const* d_in, const int* in_sizes, int n_in,
                              void* d_out, int out_size, void* d_ws, size_t ws_size,
                              hipStream_t stream) {
  const int* sent = (const int*)d_in[0];
  const int* bush = (const int*)d_in[1];
  const float* pin = (const float*)d_in[2];
  const float* wz = (const float*)d_in[3];
  const float* twz = (const float*)d_in[4];
  const int* tags = (const int*)d_in[5];
  const int* lens = (const int*)d_in[6];
  const float* emb1 = (const float*)d_in[7];
  const float* emb2 = (const float*)d_in[8];
  const float* Wq = (const float*)d_in[9];  const float* bq = (const float*)d_in[10];
  const float* Wk = (const float*)d_in[11]; const float* bk = (const float*)d_in[12];
  const float* Wv = (const float*)d_in[13]; const float* bv = (const float*)d_in[14];
  const float* Wo = (const float*)d_in[15]; const float* bo = (const float*)d_in[16];
  const float* Wihf = (const float*)d_in[17]; const float* Whhf = (const float*)d_in[18];
  const float* bihf = (const float*)d_in[19]; const float* bhhf = (const float*)d_in[20];
  const float* Wihb = (const float*)d_in[21]; const float* Whhb = (const float*)d_in[22];
  const float* bihb = (const float*)d_in[23]; const float* bhhb = (const float*)d_in[24];
  const float* Wout = (const float*)d_in[25]; const float* bout = (const float*)d_in[26];
  const float* trans = (const float*)d_in[27];
  const float* h0 = (const float*)d_in[28]; const float* c0 = (const float*)d_in[29];
  float* out = (float*)d_out;
  float* w = (float*)d_ws;
  const size_t F = (size_t)ROWSc * DMc;  // 4194304 floats
  ushort* finb = (ushort*)w;
  ushort* axb  = (ushort*)w;
  float*  qkv  = w + F / 2;
  ushort* xob  = (ushort*)(w + F / 2);
  ushort* gxt  = (ushort*)(w + F + F / 2);
  ushort* gxb  = (ushort*)(w + 3 * F + F / 2);
  ushort* louts = (ushort*)(w + 3 * F + F / 2);
  float*  lgts = w + 5 * F + F / 2;
  size_t off = 5 * F + F / 2 + (size_t)ROWSc * NTc;
  ushort* wqkvb = (ushort*)(w + off); off += 768 * 256 / 2;
  ushort* wihbf = (ushort*)(w + off); off += 1024 * 256 / 2;
  ushort* wob   = (ushort*)(w + off); off += 256 * 256 / 2;
  ushort* whhp  = (ushort*)(w + off); off += 2 * 512 * 128 / 2;
  float* woutp = w + off; off += 20 * 256;
  float* bqkv = w + off; off += 768;
  float* bihp = w + off; off += 1024;
  float* partv = w + off;

  build_fin_k<<<ROWSc, 256, 0, stream>>>(sent, bush, pin, wz, twz, emb1, emb2, finb);
  pack_weights_k<<<256, 256, 0, stream>>>(Wq, Wk, Wv, Wo, Wihf, Wihb, bq, bk, bv, bihf, bihb,
                                          wqkvb, wihbf, wob, bqkv, bihp);
  pack_whh_k<<<64, 256, 0, stream>>>(Whhf, Whhb, whhp);
  pack_wout_k<<<20, 256, 0, stream>>>(Wout, woutp);
  mfma_gemm_k<768, false><<<dim3(128, 6), 256, 0, stream>>>(finb, wqkvb, bqkv, qkv);
  attn_k<<<Bc * 4 * 2, 256, 0, stream>>>(qkv, axb);
  mfma_gemm_k<256, true><<<dim3(128, 2), 256, 0, stream>>>(axb, wob, bo, xob);
  mfma_gemm_k<1024, true><<<dim3(128, 8), 256, 0, stream>>>(xob, wihbf, bihp, gxb);
  transpose_gx_k<<<dim3(256, 2), 256, 0, stream>>>(gxb, bhhf, bhhb, gxt);
  lstm_mfma_k<<<dim3(4, 2), 512, 0, stream>>>(gxt, whhp, h0, c0, louts);
  logits_k<<<Lc, 256, 0, stream>>>(louts, woutp, bout, lgts);
  crf_fwd_k<<<Bc, 64, 0, stream>>>(lgts, tags, lens, trans, partv);
  final_sum_k<<<1, 64, 0, stream>>>(partv, out);
}

// Round 8
// 634.876 us; speedup vs baseline: 1.4480x; 1.0243x over previous
//
#include <hip/hip_runtime.h>
#include <math.h>

namespace {
constexpr int Bc = 64, Lc = 256, DMc = 256;
constexpr int NTc = 20, START_c = 18, STOP_c = 19;
constexpr int ROWSc = Bc * Lc;  // 16384
}

typedef short short8 __attribute__((ext_vector_type(8)));
typedef float f32x4 __attribute__((ext_vector_type(4)));
typedef ushort ushort4v __attribute__((ext_vector_type(4)));

__device__ __forceinline__ ushort f2bf(float x) {
  unsigned u = __float_as_uint(x);
  unsigned r = (u + 0x7FFFu + ((u >> 16) & 1u)) >> 16;
  return (ushort)r;
}
__device__ __forceinline__ float bf2f(ushort h) {
  return __uint_as_float((unsigned)h << 16);
}
__device__ __forceinline__ float vrcp(float x) {
  float r;
  asm("v_rcp_f32 %0, %1" : "=v"(r) : "v"(x));
  return r;
}
__device__ __forceinline__ float fast_sig(float x) {
  return vrcp(1.f + __expf(-x));
}
__device__ __forceinline__ float fast_tanh(float x) {
  return fmaf(-2.f, vrcp(1.f + __expf(2.f * x)), 1.f);
}
__device__ __forceinline__ unsigned cvtpk(float a, float b) {
  unsigned r;
  asm("v_cvt_pk_bf16_f32 %0, %1, %2" : "=v"(r) : "v"(a), "v"(b));
  return r;
}
__device__ __forceinline__ void lds_barrier() {
  asm volatile("s_waitcnt lgkmcnt(0)" ::: "memory");
  __builtin_amdgcn_s_barrier();
  asm volatile("" ::: "memory");
}

// ---------------- fin (bf16) = concat(emb1[sent], emb2[bush], pinyin, trans_weizhi, weizhi) ----------------
__global__ __launch_bounds__(256) void build_fin_k(
    const int* __restrict__ sent, const int* __restrict__ bush,
    const float* __restrict__ pin, const float* __restrict__ wz,
    const float* __restrict__ twz, const float* __restrict__ emb1,
    const float* __restrict__ emb2, ushort* __restrict__ finb) {
  const int row = blockIdx.x;
  const int c = threadIdx.x;
  float v;
  if (c < 100)      v = emb1[(size_t)sent[row] * 100 + c];
  else if (c < 200) v = emb2[(size_t)bush[row] * 100 + (c - 100)];
  else if (c < 220) v = pin[(size_t)row * 20 + (c - 200)];
  else if (c < 238) v = twz[(size_t)row * 18 + (c - 220)];
  else              v = wz[(size_t)row * 18 + (c - 238)];
  finb[(size_t)row * 256 + c] = f2bf(v);
}

// ---------------- pack weights/biases to bf16 (wqkv, wih) ----------------
__global__ __launch_bounds__(256) void pack_weights_k(
    const float* __restrict__ Wq, const float* __restrict__ Wk,
    const float* __restrict__ Wv,
    const float* __restrict__ Wihf, const float* __restrict__ Wihb,
    const float* __restrict__ bq, const float* __restrict__ bk,
    const float* __restrict__ bv,
    ushort* __restrict__ wqkv, ushort* __restrict__ wih,
    float* __restrict__ bqkv) {
  const int gid = blockIdx.x * 256 + threadIdx.x;  // 57344 threads
  const int row = gid >> 5;
  if (row >= 1792) return;
  const int cl = (gid & 31) * 8;
  const float* src;
  ushort* dst;
  if (row < 768) {
    src = (row < 256 ? Wq : (row < 512 ? Wk : Wv)) + (size_t)(row & 255) * 256;
    dst = wqkv + (size_t)row * 256;
  } else {
    const int rr = row - 768;
    src = (rr < 512 ? Wihf + (size_t)rr * 256 : Wihb + (size_t)(rr - 512) * 256);
    dst = wih + (size_t)rr * 256;
  }
  float4 v0 = *(const float4*)(src + cl);
  float4 v1 = *(const float4*)(src + cl + 4);
  short8 o;
  o[0] = (short)f2bf(v0.x); o[1] = (short)f2bf(v0.y); o[2] = (short)f2bf(v0.z); o[3] = (short)f2bf(v0.w);
  o[4] = (short)f2bf(v1.x); o[5] = (short)f2bf(v1.y); o[6] = (short)f2bf(v1.z); o[7] = (short)f2bf(v1.w);
  *(short8*)(dst + cl) = o;
  if (gid < 768) {
    bqkv[gid] = (gid < 256 ? bq[gid] : (gid < 512 ? bk[gid - 256] : bv[gid - 512]));
  }
}

// ---------------- woT[k][n] = Wo[n][k] (bf16) ----------------
__global__ __launch_bounds__(256) void pack_woT_k(
    const float* __restrict__ Wo, ushort* __restrict__ woT) {
  const int o = blockIdx.x * 256 + threadIdx.x;  // 65536
  const int k = o >> 8, n = o & 255;
  woT[o] = f2bf(Wo[n * 256 + k]);
}

// ---------------- bcomb[j] = bih[j] + Wih[j,:].bo ----------------
__global__ __launch_bounds__(256) void bcomb_k(
    const float* __restrict__ Wihf, const float* __restrict__ Wihb,
    const float* __restrict__ bihf, const float* __restrict__ bihb,
    const float* __restrict__ bo, float* __restrict__ bcomb) {
  const int j = blockIdx.x * 256 + threadIdx.x;  // 1024
  const float* wr = (j < 512) ? (Wihf + (size_t)j * 256) : (Wihb + (size_t)(j - 512) * 256);
  float s = (j < 512) ? bihf[j] : bihb[j - 512];
  for (int k = 0; k < 256; k += 4) {
    float4 w4 = *(const float4*)(wr + k);
    float4 b4 = *(const float4*)(bo + k);
    s += w4.x * b4.x + w4.y * b4.y + w4.z * b4.z + w4.w * b4.w;
  }
  bcomb[j] = s;
}

// ---------------- pack Whh (2x512x128) to bf16 ----------------
__global__ __launch_bounds__(256) void pack_whh_k(
    const float* __restrict__ Whhf, const float* __restrict__ Whhb,
    ushort* __restrict__ whh) {
  const int gid = blockIdx.x * 256 + threadIdx.x;  // 16384 threads
  const int idx = gid * 8;
  const float* src = (idx < 65536) ? (Whhf + idx) : (Whhb + (idx - 65536));
  float4 v0 = *(const float4*)(src);
  float4 v1 = *(const float4*)(src + 4);
  short8 o;
  o[0] = (short)f2bf(v0.x); o[1] = (short)f2bf(v0.y); o[2] = (short)f2bf(v0.z); o[3] = (short)f2bf(v0.w);
  o[4] = (short)f2bf(v1.x); o[5] = (short)f2bf(v1.y); o[6] = (short)f2bf(v1.z); o[7] = (short)f2bf(v1.w);
  *(short8*)(whh + idx) = o;
}

// ---------------- permute Wout to [n][pc][uu] order matching louts layout ----------------
__global__ __launch_bounds__(256) void pack_wout_k(
    const float* __restrict__ Wout, float* __restrict__ woutp) {
  const int o = blockIdx.x * 256 + threadIdx.x;
  if (o >= 20 * 256) return;
  const int n = o >> 8, rest = o & 255;
  const int pc = rest >> 2, uu = rest & 3;
  const int dir = pc >> 5, w = (pc >> 2) & 7, kg = pc & 3;
  woutp[o] = Wout[n * 256 + dir * 128 + w * 16 + kg * 4 + uu];
}

// ---------------- bf16 MFMA GEMM with LDS-staged A (XOR-swizzled): C = A*W^T + bias ----------------
template <int N, bool BF16_OUT>
__global__ __launch_bounds__(256, 2) void mfma_gemm_k(
    const ushort* __restrict__ A, const ushort* __restrict__ W,
    const float* __restrict__ bias, void* __restrict__ Cv) {
  __shared__ __align__(16) ushort As[128 * 256];  // 64KB
  const int tid = threadIdx.x, lane = tid & 63, wid = tid >> 6;
  const int bm = blockIdx.x * 128, bn = blockIdx.y * 128;
  const int wm = (wid >> 1) * 64, wn = (wid & 1) * 64;
  const int r = lane & 15, kg = lane >> 4;
  // stage A tile [128][256]: coalesced short8 loads, XOR-swizzled 16B-slot stores
#pragma unroll
  for (int i = 0; i < 16; ++i) {
    const int c = i * 256 + tid;          // 4096 chunks of 8 el
    const int row = c >> 5, kc = c & 31;
    short8 v = *(const short8*)(A + (size_t)(bm + row) * 256 + kc * 8);
    *(short8*)((char*)As + row * 512 + ((kc * 16) ^ ((row & 7) << 4))) = v;
  }
  const ushort* Wp = W + (size_t)(bn + wn + r) * 256 + kg * 8;
  f32x4 acc[4][4];
#pragma unroll
  for (int i = 0; i < 4; ++i)
#pragma unroll
    for (int j = 0; j < 4; ++j) acc[i][j] = (f32x4){0.f, 0.f, 0.f, 0.f};
  __syncthreads();
#pragma unroll
  for (int k0 = 0; k0 < 256; k0 += 32) {
    short8 a[4], b[4];
#pragma unroll
    for (int fi = 0; fi < 4; ++fi) {
      const int row = wm + fi * 16 + r;
      a[fi] = *(const short8*)((const char*)As + row * 512 +
                               ((k0 * 2 + kg * 16) ^ ((row & 7) << 4)));
    }
#pragma unroll
    for (int fj = 0; fj < 4; ++fj) b[fj] = *(const short8*)(Wp + fj * 16 * 256 + k0);
#pragma unroll
    for (int fi = 0; fi < 4; ++fi)
#pragma unroll
      for (int fj = 0; fj < 4; ++fj)
        acc[fi][fj] = __builtin_amdgcn_mfma_f32_16x16x32_bf16(a[fi], b[fj], acc[fi][fj], 0, 0, 0);
  }
#pragma unroll
  for (int fi = 0; fi < 4; ++fi)
#pragma unroll
    for (int fj = 0; fj < 4; ++fj) {
      const int n = bn + wn + fj * 16 + r;
      const float bn_ = bias[n];
#pragma unroll
      for (int rr = 0; rr < 4; ++rr) {
        const int m = bm + wm + fi * 16 + kg * 4 + rr;
        const float v = acc[fi][fj][rr] + bn_;
        if (BF16_OUT) ((ushort*)Cv)[(size_t)m * N + n] = f2bf(v);
        else          ((float*)Cv)[(size_t)m * N + n] = v;
      }
    }
}

// ---------------- attention: block (b,h,qhalf); qkv bf16 [ROWS][768]; out bf16 ----------
__global__ __launch_bounds__(256) void attn_k(
    const ushort* __restrict__ qkv, ushort* __restrict__ xout) {
  const int bh = blockIdx.x >> 1, qh = blockIdx.x & 1;
  const int b = bh >> 2, h = bh & 3;
  const int tid = threadIdx.x;
  const int lane = tid & 63, w = tid >> 6;
  __shared__ __align__(16) float qs[4][64];
  __shared__ __align__(16) float pl[4][256];
  __shared__ float red[4][4];
  __shared__ float pvp[4][4][64];
  __shared__ __align__(16) ushort stg[256 * 66];  // K: [256][66]; then V: [64][258]
  const ushort* qb = qkv + (size_t)(b * Lc) * 768 + h * 64;
  const ushort* kb = qb + 256;
  const ushort* vb = qb + 512;
  const int srow = tid >> 2, part = tid & 3;
  // --- stage K (bf16 copy, coalesced-ish) ---
#pragma unroll
  for (int pass = 0; pass < 4; ++pass) {
    const int row = pass * 64 + srow;
#pragma unroll
    for (int qq = 0; qq < 2; ++qq) {
      short8 v = *(const short8*)(kb + (size_t)row * 768 + qq * 32 + part * 8);
      *(short8*)(stg + row * 66 + qq * 32 + part * 8) = v;
    }
  }
  __syncthreads();
  float4 kr4[16];
#pragma unroll
  for (int j = 0; j < 16; ++j) {
    ushort4v u = *(const ushort4v*)(stg + tid * 66 + j * 4);
    kr4[j] = make_float4(bf2f(u[0]), bf2f(u[1]), bf2f(u[2]), bf2f(u[3]));
  }
  __syncthreads();
  // --- stage V transposed [d][key] ---
#pragma unroll
  for (int pass = 0; pass < 4; ++pass) {
    const int row = pass * 64 + srow;
#pragma unroll
    for (int qq = 0; qq < 2; ++qq) {
      short8 v = *(const short8*)(vb + (size_t)row * 768 + qq * 32 + part * 8);
      const int d0 = qq * 32 + part * 8;
#pragma unroll
      for (int i = 0; i < 8; ++i) stg[(d0 + i) * 258 + row] = (ushort)v[i];
    }
  }
  __syncthreads();
  float4 vr4[16];
#pragma unroll
  for (int j4 = 0; j4 < 16; ++j4) {
    ushort4v u = *(const ushort4v*)(stg + lane * 258 + w * 64 + j4 * 4);
    vr4[j4] = make_float4(bf2f(u[0]), bf2f(u[1]), bf2f(u[2]), bf2f(u[3]));
  }

  for (int q0 = qh * 128; q0 < qh * 128 + 128; q0 += 4) {
    lds_barrier();
    qs[w][lane] = bf2f(qb[(size_t)(q0 + w) * 768 + lane]);
    lds_barrier();
    float s0 = 0, s1 = 0, s2 = 0, s3 = 0;
#pragma unroll
    for (int d4 = 0; d4 < 16; ++d4) {
      float4 kv = kr4[d4];
      float4 q0v = *(const float4*)(&qs[0][d4 * 4]);
      float4 q1v = *(const float4*)(&qs[1][d4 * 4]);
      float4 q2v = *(const float4*)(&qs[2][d4 * 4]);
      float4 q3v = *(const float4*)(&qs[3][d4 * 4]);
      s0 += kv.x * q0v.x + kv.y * q0v.y + kv.z * q0v.z + kv.w * q0v.w;
      s1 += kv.x * q1v.x + kv.y * q1v.y + kv.z * q1v.z + kv.w * q1v.w;
      s2 += kv.x * q2v.x + kv.y * q2v.y + kv.z * q2v.z + kv.w * q2v.w;
      s3 += kv.x * q3v.x + kv.y * q3v.y + kv.z * q3v.z + kv.w * q3v.w;
    }
    s0 *= 0.125f; s1 *= 0.125f; s2 *= 0.125f; s3 *= 0.125f;
    float m0 = s0, m1 = s1, m2 = s2, m3 = s3;
#pragma unroll
    for (int off = 32; off > 0; off >>= 1) {
      m0 = fmaxf(m0, __shfl_xor(m0, off));
      m1 = fmaxf(m1, __shfl_xor(m1, off));
      m2 = fmaxf(m2, __shfl_xor(m2, off));
      m3 = fmaxf(m3, __shfl_xor(m3, off));
    }
    if (lane == 0) { red[w][0] = m0; red[w][1] = m1; red[w][2] = m2; red[w][3] = m3; }
    lds_barrier();
    const float M0 = fmaxf(fmaxf(red[0][0], red[1][0]), fmaxf(red[2][0], red[3][0]));
    const float M1 = fmaxf(fmaxf(red[0][1], red[1][1]), fmaxf(red[2][1], red[3][1]));
    const float M2 = fmaxf(fmaxf(red[0][2], red[1][2]), fmaxf(red[2][2], red[3][2]));
    const float M3 = fmaxf(fmaxf(red[0][3], red[1][3]), fmaxf(red[2][3], red[3][3]));
    const float e0 = __expf(s0 - M0), e1 = __expf(s1 - M1), e2 = __expf(s2 - M2), e3 = __expf(s3 - M3);
    pl[0][tid] = e0; pl[1][tid] = e1; pl[2][tid] = e2; pl[3][tid] = e3;
    float t0 = e0, t1 = e1, t2 = e2, t3 = e3;
#pragma unroll
    for (int off = 32; off > 0; off >>= 1) {
      t0 += __shfl_xor(t0, off); t1 += __shfl_xor(t1, off);
      t2 += __shfl_xor(t2, off); t3 += __shfl_xor(t3, off);
    }
    lds_barrier();
    if (lane == 0) { red[w][0] = t0; red[w][1] = t1; red[w][2] = t2; red[w][3] = t3; }
    lds_barrier();
    float a0 = 0, a1 = 0, a2 = 0, a3 = 0;
#pragma unroll
    for (int j4 = 0; j4 < 16; ++j4) {
      float4 vv = vr4[j4];
      float4 p0 = *(const float4*)(&pl[0][w * 64 + j4 * 4]);
      float4 p1 = *(const float4*)(&pl[1][w * 64 + j4 * 4]);
      float4 p2 = *(const float4*)(&pl[2][w * 64 + j4 * 4]);
      float4 p3 = *(const float4*)(&pl[3][w * 64 + j4 * 4]);
      a0 += p0.x * vv.x + p0.y * vv.y + p0.z * vv.z + p0.w * vv.w;
      a1 += p1.x * vv.x + p1.y * vv.y + p1.z * vv.z + p1.w * vv.w;
      a2 += p2.x * vv.x + p2.y * vv.y + p2.z * vv.z + p2.w * vv.w;
      a3 += p3.x * vv.x + p3.y * vv.y + p3.z * vv.z + p3.w * vv.w;
    }
    pvp[w][0][lane] = a0; pvp[w][1][lane] = a1; pvp[w][2][lane] = a2; pvp[w][3][lane] = a3;
    lds_barrier();
    const float den = red[0][w] + red[1][w] + red[2][w] + red[3][w];
    const float rres = (pvp[0][w][lane] + pvp[1][w][lane] + pvp[2][w][lane] + pvp[3][w][lane]) * vrcp(den);
    xout[((size_t)b * Lc + q0 + w) * 256 + h * 64 + lane] = f2bf(rres);
  }
}

// ---------------- transpose gx -> gxt [s][dir][grow][b][r], folding in bhh ----------------
__global__ __launch_bounds__(256) void transpose_gx_k(
    const ushort* __restrict__ gx, const float* __restrict__ bhhf,
    const float* __restrict__ bhhb, ushort* __restrict__ gxt) {
  const int s = blockIdx.x, dir = blockIdx.y;
  const int t = threadIdx.x;
  const int b = t & 63;
  const int c = t >> 6;  // wave 0..3
  const float* bhh = dir ? bhhb : bhhf;
  const size_t obase = (size_t)(s * 2 + dir) * 32768;
#pragma unroll 4
  for (int i = 0; i < 16; ++i) {
    const int g8 = i * 4 + c;  // 0..63
    short8 v = *(const short8*)(gx + ((size_t)b * 256 + s) * 1024 + dir * 512 + g8 * 8);
    float f[8];
#pragma unroll
    for (int j = 0; j < 8; ++j) f[j] = bf2f((ushort)v[j]) + bhh[g8 * 8 + j];
    uint2 lo = make_uint2(cvtpk(f[0], f[1]), cvtpk(f[2], f[3]));
    uint2 hi = make_uint2(cvtpk(f[4], f[5]), cvtpk(f[6], f[7]));
    *(uint2*)(gxt + obase + (size_t)(g8 * 2) * 256 + b * 4) = lo;
    *(uint2*)(gxt + obase + (size_t)(g8 * 2 + 1) * 256 + b * 4) = hi;
  }
}

// ---------------- MFMA BiLSTM (unchanged from R7) ----------------
__global__ __launch_bounds__(512, 2) void lstm_mfma_k(
    const ushort* __restrict__ gxt, const ushort* __restrict__ whh,
    const float* __restrict__ h0, const float* __restrict__ c0,
    ushort* __restrict__ louts) {
  const int bs = blockIdx.x * 16;
  const int dir = blockIdx.y;
  const int tid = threadIdx.x;
  const int w = tid >> 6, lane = tid & 63;
  const int col = lane & 15;
  const int kg = lane >> 4;
  short8 afrag[4][4];
#pragma unroll
  for (int g = 0; g < 4; ++g)
#pragma unroll
    for (int ks = 0; ks < 4; ++ks)
      afrag[g][ks] = *(const short8*)(whh + (size_t)dir * 65536 +
                                      (size_t)(g * 128 + w * 16 + col) * 128 + ks * 32 + kg * 8);
  float4 c4 = *(const float4*)(c0 + (size_t)(dir * Bc + bs + col) * 128 + w * 16 + kg * 4);
  __shared__ __align__(16) ushort hlds[2][2048];
  {
    float4 h4 = *(const float4*)(h0 + (size_t)(dir * Bc + bs + col) * 128 + w * 16 + kg * 4);
    const int wb = (col * 256 + w * 32 + kg * 8) ^ ((col & 7) << 4);
    *(uint2*)((char*)hlds[0] + wb) = make_uint2(cvtpk(h4.x, h4.y), cvtpk(h4.z, h4.w));
  }
  const ushort* gtb = gxt + (size_t)dir * 32768 + (size_t)(w * 4 + kg) * 256 + (size_t)(bs + col) * 4;
  int step = dir ? (Lc - 1) : 0;
  const int dstep = dir ? -1 : 1;
  ushort4v gA[4], gB[4];
#pragma unroll
  for (int g = 0; g < 4; ++g) gA[g] = *(const ushort4v*)(gtb + (size_t)step * 65536 + g * 8192);
#pragma unroll
  for (int g = 0; g < 4; ++g) gB[g] = *(const ushort4v*)(gtb + (size_t)(step + dstep) * 65536 + g * 8192);
  __syncthreads();
  int p = 0;

  auto body = [&](ushort4v (&gcur)[4], int pfstep, bool pfok) {
    short8 bfrag[4];
#pragma unroll
    for (int ks = 0; ks < 4; ++ks) {
      const int rb = (col * 256 + ks * 64 + kg * 16) ^ ((col & 7) << 4);
      bfrag[ks] = *(const short8*)((const char*)hlds[p] + rb);
    }
    f32x4 acc[4];
#pragma unroll
    for (int g = 0; g < 4; ++g)
      acc[g] = (f32x4){bf2f(gcur[g][0]), bf2f(gcur[g][1]), bf2f(gcur[g][2]), bf2f(gcur[g][3])};
    if (pfok) {
#pragma unroll
      for (int g = 0; g < 4; ++g) gcur[g] = *(const ushort4v*)(gtb + (size_t)pfstep * 65536 + g * 8192);
    }
#pragma unroll
    for (int ks = 0; ks < 4; ++ks)
#pragma unroll
      for (int g = 0; g < 4; ++g)
        acc[g] = __builtin_amdgcn_mfma_f32_16x16x32_bf16(afrag[g][ks], bfrag[ks], acc[g], 0, 0, 0);
    f32x4 hr;
#pragma unroll
    for (int r = 0; r < 4; ++r) {
      const float ii = fast_sig (acc[0][r]);
      const float ff = fast_sig (acc[1][r]);
      const float gg = fast_tanh(acc[2][r]);
      const float oo = fast_sig (acc[3][r]);
      const float cn = ff * c4[r] + ii * gg;
      c4[r] = cn;
      hr[r] = oo * fast_tanh(cn);
    }
    const uint2 hp2 = make_uint2(cvtpk(hr[0], hr[1]), cvtpk(hr[2], hr[3]));
    const int wb = (col * 256 + w * 32 + kg * 8) ^ ((col & 7) << 4);
    *(uint2*)((char*)hlds[p ^ 1] + wb) = hp2;
    *(uint2*)(louts + (size_t)step * 16384 + dir * 8192 + w * 1024 + kg * 256 +
              (size_t)(bs + col) * 4) = hp2;
    asm volatile("s_waitcnt lgkmcnt(0)" ::: "memory");
    __builtin_amdgcn_s_barrier();
    asm volatile("" ::: "memory");
    p ^= 1;
    step += dstep;
  };

  for (int s = 0; s < Lc; s += 2) {
    const int pf1 = step + 2 * dstep;
    body(gA, pf1, s + 2 < Lc);
    const int pf2 = step + 2 * dstep;
    body(gB, pf2, s + 3 < Lc);
  }
}

// ---------------- logits (unchanged) ----------------
__global__ __launch_bounds__(256) void logits_k(
    const ushort* __restrict__ louts, const float* __restrict__ woutp,
    const float* __restrict__ bout, float* __restrict__ lg) {
  const int s = blockIdx.x;
  const int t = threadIdx.x;
  __shared__ __align__(16) ushort xs[16384];
  __shared__ float wls[20 * 256];
  __shared__ float bls[20];
  {
    const ushort* src = louts + (size_t)s * 16384;
#pragma unroll
    for (int i = 0; i < 8; ++i)
      *(short8*)(xs + i * 2048 + t * 8) = *(const short8*)(src + i * 2048 + t * 8);
    for (int i = t; i < 20 * 256; i += 256) wls[i] = woutp[i];
    if (t < 20) bls[t] = bout[t];
  }
  __syncthreads();
  const int b = t & 63, tg = t >> 6;
  float acc[5] = {0.f, 0.f, 0.f, 0.f, 0.f};
  for (int pc = 0; pc < 64; ++pc) {
    ushort4v x4 = *(const ushort4v*)(xs + pc * 256 + b * 4);
    const float x0 = bf2f(x4[0]), x1 = bf2f(x4[1]), x2 = bf2f(x4[2]), x3 = bf2f(x4[3]);
#pragma unroll
    for (int n = 0; n < 5; ++n) {
      const float* w4 = wls + (tg * 5 + n) * 256 + pc * 4;
      acc[n] += x0 * w4[0] + x1 * w4[1] + x2 * w4[2] + x3 * w4[3];
    }
  }
#pragma unroll
  for (int n = 0; n < 5; ++n)
    lg[((size_t)b * Lc + s) * NTc + tg * 5 + n] = acc[n] + bls[tg * 5 + n];
}

// ---------------- CRF (unchanged) ----------------
__global__ __launch_bounds__(64) void crf_fwd_k(
    const float* __restrict__ lg, const int* __restrict__ tags,
    const int* __restrict__ lens, const float* __restrict__ tr,
    float* __restrict__ part) {
  const int b = blockIdx.x, j = threadIdx.x;
  __shared__ float prev[NTc];
  __shared__ float tl[NTc * NTc];
  if (j < NTc) prev[j] = 0.f;
  for (int i = j; i < NTc * NTc; i += 64) tl[i] = tr[i];
  __syncthreads();
  const int len = lens[b];
  float gv = 0.f;
  for (int t = j; t < len; t += 64) {
    const int tag = tags[b * Lc + t];
    const int pv = (t == 0) ? START_c : tags[b * Lc + t - 1];
    gv += lg[((size_t)b * Lc + t) * NTc + tag] + tl[pv * NTc + tag];
  }
#pragma unroll
  for (int off = 32; off > 0; off >>= 1) gv += __shfl_xor(gv, off);
  float trc[NTc];
  if (j < NTc) {
#pragma unroll
    for (int i = 0; i < NTc; ++i) trc[i] = tl[i * NTc + j];
  }
  float lgn = (j < NTc) ? lg[((size_t)b * Lc) * NTc + j] : 0.f;
  for (int t = 0; t < len; ++t) {
    const float lgc = lgn;
    float nj = 0.f;
    if (j < NTc) {
      if (t + 1 < len) lgn = lg[((size_t)b * Lc + t + 1) * NTc + j];
      float v[NTc];
      float m = -1e30f;
#pragma unroll
      for (int i = 0; i < NTc; ++i) { v[i] = prev[i] + trc[i]; m = fmaxf(m, v[i]); }
      float ssum = 0.f;
#pragma unroll
      for (int i = 0; i < NTc; ++i) ssum += __expf(v[i] - m);
      nj = m + __logf(ssum) + lgc;
    }
    __syncthreads();
    if (j < NTc) prev[j] = nj;
    __syncthreads();
  }
  if (j == 0) {
    const int lt = tags[b * Lc + len - 1];
    const float realv = gv + tl[lt * NTc + STOP_c];
    float m = -1e30f;
#pragma unroll
    for (int i = 0; i < NTc; ++i) m = fmaxf(m, prev[i] + tl[i * NTc + STOP_c]);
    float ssum = 0.f;
#pragma unroll
    for (int i = 0; i < NTc; ++i) ssum += __expf(prev[i] + tl[i * NTc + STOP_c] - m);
    part[b] = (m + __logf(ssum)) - realv;
  }
}

__global__ __launch_bounds__(64) void final_sum_k(const float* __restrict__ part, float* __restrict__ out) {
  float v = part[threadIdx.x];
#pragma unroll
  for (int off = 32; off > 0; off >>= 1) v += __shfl_down(v, off);
  if (threadIdx.x == 0) out[0] = v;
}

extern "C" void kernel_launch(void* const* d_in, const int* in_sizes, int n_in,
                              void* d_out, int out_size, void* d_ws, size_t ws_size,
                              hipStream_t stream) {
  const int* sent = (const int*)d_in[0];
  const int* bush = (const int*)d_in[1];
  const float* pin = (const float*)d_in[2];
  const float* wz = (const float*)d_in[3];
  const float* twz = (const float*)d_in[4];
  const int* tags = (const int*)d_in[5];
  const int* lens = (const int*)d_in[6];
  const float* emb1 = (const float*)d_in[7];
  const float* emb2 = (const float*)d_in[8];
  const float* Wq = (const float*)d_in[9];  const float* bq = (const float*)d_in[10];
  const float* Wk = (const float*)d_in[11]; const float* bk = (const float*)d_in[12];
  const float* Wv = (const float*)d_in[13]; const float* bv = (const float*)d_in[14];
  const float* Wo = (const float*)d_in[15]; const float* bo = (const float*)d_in[16];
  const float* Wihf = (const float*)d_in[17]; const float* Whhf = (const float*)d_in[18];
  const float* bihf = (const float*)d_in[19]; const float* bhhf = (const float*)d_in[20];
  const float* Wihb = (const float*)d_in[21]; const float* Whhb = (const float*)d_in[22];
  const float* bihb = (const float*)d_in[23]; const float* bhhb = (const float*)d_in[24];
  const float* Wout = (const float*)d_in[25]; const float* bout = (const float*)d_in[26];
  const float* trans = (const float*)d_in[27];
  const float* h0 = (const float*)d_in[28]; const float* c0 = (const float*)d_in[29];
  float* out = (float*)d_out;
  float* w = (float*)d_ws;
  // Arena (float units), total ~17.3M floats = 69 MB:
  //  [0, 2M)        finb -> axb -> (later) gxt head
  //  [2M, 8.39M)    qkv bf16 -> (later) gxt tail      (gxt = [0, 8.39M))
  //  [8.39M, 16.78M) gxb -> louts (head) ; lgts at 10.49M (gxb dead by then)
  //  [16.78M, ...)  weights/biases (never overlaid)
  ushort* finb  = (ushort*)w;
  ushort* axb   = (ushort*)w;
  ushort* qkvb  = (ushort*)(w + 2097152);
  ushort* gxb   = (ushort*)(w + 8388608);
  ushort* gxt   = (ushort*)w;
  ushort* louts = (ushort*)(w + 8388608);
  float*  lgts  = w + 10485760;
  size_t off = 16777216;
  ushort* wqkvb  = (ushort*)(w + off); off += 768 * 256 / 2;
  ushort* wihbf  = (ushort*)(w + off); off += 1024 * 256 / 2;
  ushort* woTb   = (ushort*)(w + off); off += 256 * 256 / 2;
  ushort* wcombb = (ushort*)(w + off); off += 1024 * 256 / 2;
  ushort* whhp   = (ushort*)(w + off); off += 2 * 512 * 128 / 2;
  float* woutp = w + off; off += 20 * 256;
  float* bqkv  = w + off; off += 768;
  float* bcomb = w + off; off += 1024;
  float* zbias = w + off; off += 256;
  float* partv = w + off;

  hipMemsetAsync(zbias, 0, 256 * sizeof(float), stream);
  build_fin_k<<<ROWSc, 256, 0, stream>>>(sent, bush, pin, wz, twz, emb1, emb2, finb);
  pack_weights_k<<<224, 256, 0, stream>>>(Wq, Wk, Wv, Wihf, Wihb, bq, bk, bv,
                                          wqkvb, wihbf, bqkv);
  pack_whh_k<<<64, 256, 0, stream>>>(Whhf, Whhb, whhp);
  pack_wout_k<<<20, 256, 0, stream>>>(Wout, woutp);
  pack_woT_k<<<256, 256, 0, stream>>>(Wo, woTb);
  bcomb_k<<<4, 256, 0, stream>>>(Wihf, Wihb, bihf, bihb, bo, bcomb);
  // Wcomb[j][k] = sum_n Wih[j][n] * Wo[n][k]
  mfma_gemm_k<256, true><<<dim3(8, 2), 256, 0, stream>>>(wihbf, woTb, zbias, wcombb);
  mfma_gemm_k<768, true><<<dim3(128, 6), 256, 0, stream>>>(finb, wqkvb, bqkv, qkvb);
  attn_k<<<Bc * 4 * 2, 256, 0, stream>>>(qkvb, axb);
  // gx = attn_out @ Wcomb^T + bcomb   (O-proj fused in)
  mfma_gemm_k<1024, true><<<dim3(128, 8), 256, 0, stream>>>(axb, wcombb, bcomb, gxb);
  transpose_gx_k<<<dim3(256, 2), 256, 0, stream>>>(gxb, bhhf, bhhb, gxt);
  lstm_mfma_k<<<dim3(4, 2), 512, 0, stream>>>(gxt, whhp, h0, c0, louts);
  logits_k<<<Lc, 256, 0, stream>>>(louts, woutp, bout, lgts);
  crf_fwd_k<<<Bc, 64, 0, stream>>>(lgts, tags, lens, trans, partv);
  final_sum_k<<<1, 64, 0, stream>>>(partv, out);
}